// Round 2
// baseline (339.072 us; speedup 1.0000x reference)
//
#include <hip/hip_runtime.h>

// B=2, S=2048, D=1024, H=16, DH=64. out = softmax(mask(QK^T/8)) V @ Wo^T, Q=x@Wq^T etc.
// Dtype-adaptive: detects fp32 vs bf16 per tensor group at launch (host-side query).
// Internal compute: bf16 MFMA, fp32 accum. Workspace use: 16 MB (Qp, Kp). Vt lives in
// d_out (scratch, fully overwritten by final projection). Attn output aliases Qp (safe:
// per-block disjoint read/write element sets).

typedef unsigned short u16;
typedef __attribute__((ext_vector_type(8))) short bf16x8;  // 8 bf16 = 4 VGPR
typedef __attribute__((ext_vector_type(4))) float f32x4;   // MFMA C/D frag
typedef __attribute__((ext_vector_type(4))) short s16x4;

#define DEVI static __device__ __forceinline__

DEVI u16 f2bf(float f) {
  union { float f; unsigned u; } v; v.f = f;
  unsigned r = v.u + 0x7FFFu + ((v.u >> 16) & 1u);  // RNE
  return (u16)(r >> 16);
}

// Load 8 contiguous elements at element-offset `off`, as bf16x8.
template <int F32>
DEVI bf16x8 lda8(const void* base, size_t off) {
  if constexpr (!F32) {
    return *(const bf16x8*)((const u16*)base + off);
  } else {
    const float* p = (const float*)base + off;
    f32x4 a = *(const f32x4*)p;
    f32x4 b = *(const f32x4*)(p + 4);
    bf16x8 r;
    r[0] = (short)f2bf(a[0]); r[1] = (short)f2bf(a[1]);
    r[2] = (short)f2bf(a[2]); r[3] = (short)f2bf(a[3]);
    r[4] = (short)f2bf(b[0]); r[5] = (short)f2bf(b[1]);
    r[6] = (short)f2bf(b[2]); r[7] = (short)f2bf(b[3]);
    return r;
  }
}

// C = A[4096,1024] @ W[1024,1024]^T. MODE 0: row-major store (bf16 or f32 per O32).
// MODE 1: V-transpose store Vt[((b*16+h)*64+d)*2048 + s], always bf16.
template <int A32, int W32, int MODE, int O32>
DEVI void gemm_core(u16* sA, u16* sB, const void* A, const void* W, void* C) {
  constexpr int K = 1024, N = 1024;
  const int tid = threadIdx.x;
  const int lane = tid & 63;
  const int wave = tid >> 6;
  const int tileM = blockIdx.y * 128;
  const int tileN = blockIdx.x * 128;
  const int wr = (wave >> 1) * 64;
  const int wc = (wave & 1) * 64;
  const int lr = lane & 15;
  const int lg = lane >> 4;

  f32x4 acc[4][4] = {};

  const int e0 = tid * 8;
  const int e1 = 2048 + tid * 8;
  const int r0 = e0 >> 5, c0 = e0 & 31;
  const int r1 = e1 >> 5, c1 = e1 & 31;

  for (int k0 = 0; k0 < K; k0 += 32) {
    bf16x8 va0 = lda8<A32>(A, (size_t)(tileM + r0) * K + c0 + k0);
    bf16x8 va1 = lda8<A32>(A, (size_t)(tileM + r1) * K + c1 + k0);
    bf16x8 vb0 = lda8<W32>(W, (size_t)(tileN + r0) * K + c0 + k0);
    bf16x8 vb1 = lda8<W32>(W, (size_t)(tileN + r1) * K + c1 + k0);
    __syncthreads();
    *(bf16x8*)(sA + e0) = va0;
    *(bf16x8*)(sA + e1) = va1;
    *(bf16x8*)(sB + e0) = vb0;
    *(bf16x8*)(sB + e1) = vb1;
    __syncthreads();
    bf16x8 af[4], bfr[4];
#pragma unroll
    for (int m = 0; m < 4; ++m)
      af[m] = *(const bf16x8*)(sA + (wr + m * 16 + lr) * 32 + lg * 8);
#pragma unroll
    for (int n = 0; n < 4; ++n)
      bfr[n] = *(const bf16x8*)(sB + (wc + n * 16 + lr) * 32 + lg * 8);
#pragma unroll
    for (int m = 0; m < 4; ++m)
#pragma unroll
      for (int n = 0; n < 4; ++n)
        acc[m][n] = __builtin_amdgcn_mfma_f32_16x16x32_bf16(af[m], bfr[n], acc[m][n], 0, 0, 0);
  }

  if constexpr (MODE == 0) {
#pragma unroll
    for (int m = 0; m < 4; ++m) {
      const int row0 = tileM + wr + m * 16 + lg * 4;
#pragma unroll
      for (int n = 0; n < 4; ++n) {
        const int col = tileN + wc + n * 16 + lr;
#pragma unroll
        for (int j = 0; j < 4; ++j) {
          if constexpr (O32)
            ((float*)C)[(size_t)(row0 + j) * N + col] = acc[m][n][j];
          else
            ((u16*)C)[(size_t)(row0 + j) * N + col] = f2bf(acc[m][n][j]);
        }
      }
    }
  } else {
    u16* Cv = (u16*)C;
#pragma unroll
    for (int m = 0; m < 4; ++m) {
      const int row0 = tileM + wr + m * 16 + lg * 4;
      const int b = row0 >> 11, s0 = row0 & 2047;
#pragma unroll
      for (int n = 0; n < 4; ++n) {
        const int col = tileN + wc + n * 16 + lr;
        s16x4 pk;
#pragma unroll
        for (int j = 0; j < 4; ++j) pk[j] = (short)f2bf(acc[m][n][j]);
        *(s16x4*)(Cv + ((size_t)(col + (b << 10)) << 11) + s0) = pk;  // 4 consecutive s
      }
    }
  }
}

template <int IN32>
__global__ void __launch_bounds__(256)
gemm_qkv(const void* __restrict__ q, const void* __restrict__ wq, u16* __restrict__ Qp,
         const void* __restrict__ k, const void* __restrict__ wk, u16* __restrict__ Kp,
         const void* __restrict__ v, const void* __restrict__ wv, u16* __restrict__ Vt) {
  __shared__ u16 sA[128 * 32];
  __shared__ u16 sB[128 * 32];
  if (blockIdx.z == 0)      gemm_core<IN32, IN32, 0, 0>(sA, sB, q, wq, Qp);
  else if (blockIdx.z == 1) gemm_core<IN32, IN32, 0, 0>(sA, sB, k, wk, Kp);
  else                      gemm_core<IN32, IN32, 1, 0>(sA, sB, v, wv, Vt);
}

template <int W32, int O32>
__global__ void __launch_bounds__(256)
gemm_out(const u16* __restrict__ A, const void* __restrict__ W, void* __restrict__ C) {
  __shared__ u16 sA[128 * 32];
  __shared__ u16 sB[128 * 32];
  gemm_core<0, W32, 0, O32>(sA, sB, A, W, C);
}

// Flash attention, causal. Grid: x = S/64, y = B*H. 4 independent waves/block,
// 16 q-rows/wave, 32 keys/iter. AO may alias Qp (disjoint per-block elements).
__global__ void __launch_bounds__(256)
attn_kernel(const u16* __restrict__ Qp, const u16* __restrict__ Kp,
            const u16* __restrict__ Vt, u16* __restrict__ AO) {
  const int tid = threadIdx.x;
  const int lane = tid & 63;
  const int wave = tid >> 6;
  const int lr = lane & 15;
  const int lg = lane >> 4;
  const int bh = blockIdx.y;
  const int b = bh >> 4;
  const int h = bh & 15;
  const int q0 = blockIdx.x * 64 + wave * 16;

  __shared__ u16 p_lds[4][16 * 32];
  u16* pl = &p_lds[wave][0];

  const u16* Qb = Qp + ((size_t)(b * 2048 + q0) << 10) + h * 64;
  const bf16x8 qf0 = *(const bf16x8*)(Qb + lr * 1024 + lg * 8);
  const bf16x8 qf1 = *(const bf16x8*)(Qb + lr * 1024 + 32 + lg * 8);

  const u16* Kb = Kp + ((size_t)(b * 2048) << 10) + h * 64;
  const u16* Vb = Vt + ((size_t)(bh * 64) << 11);  // [dh][s], stride 2048

  f32x4 o[4] = {};
  float mr[4] = {-INFINITY, -INFINITY, -INFINITY, -INFINITY};
  float ls[4] = {0.f, 0.f, 0.f, 0.f};

  const int kend = q0 + 15;
  for (int kt = 0; kt <= kend; kt += 32) {
    const u16* K0 = Kb + (size_t)(kt + lr) * 1024 + lg * 8;
    const u16* K1 = Kb + (size_t)(kt + 16 + lr) * 1024 + lg * 8;
    const bf16x8 kf00 = *(const bf16x8*)(K0);
    const bf16x8 kf01 = *(const bf16x8*)(K0 + 32);
    const bf16x8 kf10 = *(const bf16x8*)(K1);
    const bf16x8 kf11 = *(const bf16x8*)(K1 + 32);

    const f32x4 z = {};
    f32x4 s0 = __builtin_amdgcn_mfma_f32_16x16x32_bf16(qf0, kf00, z, 0, 0, 0);
    s0 = __builtin_amdgcn_mfma_f32_16x16x32_bf16(qf1, kf01, s0, 0, 0, 0);
    f32x4 s1 = __builtin_amdgcn_mfma_f32_16x16x32_bf16(qf0, kf10, z, 0, 0, 0);
    s1 = __builtin_amdgcn_mfma_f32_16x16x32_bf16(qf1, kf11, s1, 0, 0, 0);

    float a0[4], a1[4], tm[4];
#pragma unroll
    for (int j = 0; j < 4; ++j) {
      const int qrow = q0 + lg * 4 + j;
      a0[j] = (kt + lr > qrow) ? -INFINITY : s0[j] * 0.125f;
      a1[j] = (kt + 16 + lr > qrow) ? -INFINITY : s1[j] * 0.125f;
      tm[j] = fmaxf(a0[j], a1[j]);
    }
#pragma unroll
    for (int off = 1; off < 16; off <<= 1)
#pragma unroll
      for (int j = 0; j < 4; ++j)
        tm[j] = fmaxf(tm[j], __shfl_xor(tm[j], off));

    float fac[4], p0[4], p1[4], ts[4];
#pragma unroll
    for (int j = 0; j < 4; ++j) {
      const float mn = fmaxf(mr[j], tm[j]);
      fac[j] = __expf(mr[j] - mn);
      mr[j] = mn;
      p0[j] = __expf(a0[j] - mn);
      p1[j] = __expf(a1[j] - mn);
      ts[j] = p0[j] + p1[j];
    }
#pragma unroll
    for (int off = 1; off < 16; off <<= 1)
#pragma unroll
      for (int j = 0; j < 4; ++j)
        ts[j] += __shfl_xor(ts[j], off);
#pragma unroll
    for (int j = 0; j < 4; ++j) ls[j] = ls[j] * fac[j] + ts[j];
#pragma unroll
    for (int d = 0; d < 4; ++d)
#pragma unroll
      for (int j = 0; j < 4; ++j) o[d][j] *= fac[j];

#pragma unroll
    for (int j = 0; j < 4; ++j) {
      pl[(lg * 4 + j) * 32 + lr] = f2bf(p0[j]);
      pl[(lg * 4 + j) * 32 + 16 + lr] = f2bf(p1[j]);
    }
    asm volatile("s_waitcnt lgkmcnt(0)" ::: "memory");
    const bf16x8 pa = *(const bf16x8*)(pl + lr * 32 + lg * 8);

#pragma unroll
    for (int d = 0; d < 4; ++d) {
      const bf16x8 vf = *(const bf16x8*)(Vb + (size_t)(16 * d + lr) * 2048 + kt + lg * 8);
      o[d] = __builtin_amdgcn_mfma_f32_16x16x32_bf16(pa, vf, o[d], 0, 0, 0);
    }
  }

  const size_t orow = (size_t)(b * 2048 + q0 + lg * 4);
#pragma unroll
  for (int d = 0; d < 4; ++d) {
    const int col = h * 64 + 16 * d + lr;
#pragma unroll
    for (int j = 0; j < 4; ++j)
      AO[(orow + j) * 1024 + col] = f2bf(o[d][j] / ls[j]);
  }
}

// Host-side bytes/element detection: exact-adjacency first (slab layout), then
// allocation-size query. Pure host queries; no stream interaction (capture-safe).
static int bytes_per_elem(void* p, long long n, void* pnext) {
  if (pnext) {
    ptrdiff_t d = (char*)pnext - (char*)p;
    if (d == n * 2) return 2;
    if (d == n * 4) return 4;
  }
  size_t sz = 0;
  if (hipMemPtrGetInfo(p, &sz) == hipSuccess && sz >= (size_t)(n * 2)) {
    if (sz < (size_t)(n * 4)) return 2;       // only bf16 fits
    if (sz <= (size_t)(n * 8)) return 4;      // exact-ish fp32 alloc
  }
  return 4;  // default: fp32 (bf16 interpretation empirically NaN'd in R1)
}

extern "C" void kernel_launch(void* const* d_in, const int* in_sizes, int n_in,
                              void* d_out, int out_size, void* d_ws, size_t ws_size,
                              hipStream_t stream) {
  void* q  = d_in[0];
  void* k  = d_in[1];
  void* v  = d_in[2];
  // d_in[3] = causal tril mask (int32) -- hardcoded in attn_kernel
  void* wq = d_in[4];
  void* wk = d_in[5];
  void* wv = d_in[6];
  void* wo = d_in[7];

  const int in32 = bytes_per_elem(q, in_sizes[0], k) == 4;
  const int w32  = bytes_per_elem(wq, in_sizes[4], wk) == 4;
  const int o32  = bytes_per_elem(d_out, out_size, nullptr) == 4;

  const size_t SZ = (size_t)4096 * 1024;
  u16* Qp = (u16*)d_ws;        // [B,S,D] bf16
  u16* Kp = Qp + SZ;           // [B,S,D] bf16
  u16* Vt = (u16*)d_out;       // [B,H,DH,S] bf16 scratch; overwritten by gemm_out
  u16* AO = Qp;                // attn out aliases Qp (disjoint per-block elements)

  if (in32)
    gemm_qkv<1><<<dim3(8, 32, 3), 256, 0, stream>>>(q, wq, Qp, k, wk, Kp, v, wv, Vt);
  else
    gemm_qkv<0><<<dim3(8, 32, 3), 256, 0, stream>>>(q, wq, Qp, k, wk, Kp, v, wv, Vt);

  attn_kernel<<<dim3(32, 32), 256, 0, stream>>>(Qp, Kp, Vt, AO);

  if (w32) {
    if (o32) gemm_out<1, 1><<<dim3(8, 32), 256, 0, stream>>>(AO, wo, d_out);
    else     gemm_out<1, 0><<<dim3(8, 32), 256, 0, stream>>>(AO, wo, d_out);
  } else {
    if (o32) gemm_out<0, 1><<<dim3(8, 32), 256, 0, stream>>>(AO, wo, d_out);
    else     gemm_out<0, 0><<<dim3(8, 32), 256, 0, stream>>>(AO, wo, d_out);
  }
}

// Round 3
// 316.978 us; speedup vs baseline: 1.0697x; 1.0697x over previous
//
#include <hip/hip_runtime.h>
#include <hip/hip_bf16.h>

// B=2, S=2048, D=1024, H=16, DH=64. out = softmax(mask(QK^T/8)) V @ Wo^T, Q=x@Wq^T etc.
// Inputs fp32 (detected at launch; bf16 fallback kept). Internal: bf16 MFMA, fp32 accum.

typedef unsigned short u16;
typedef __attribute__((ext_vector_type(8))) short bf16x8;  // 8 bf16 = 4 VGPR
typedef __attribute__((ext_vector_type(4))) float f32x4;   // MFMA C/D frag
typedef __attribute__((ext_vector_type(4))) short s16x4;

#define DEVI static __device__ __forceinline__

DEVI u16 f2bf(float f) {
  __hip_bfloat16 h = __float2bfloat16(f);  // HW RNE; compiler pairs into v_cvt_pk_bf16_f32
  union { __hip_bfloat16 h; u16 u; } c; c.h = h;
  return c.u;
}

// Load 8 contiguous elements at element-offset `off`, as bf16x8.
template <int F32>
DEVI bf16x8 lda8(const void* base, size_t off) {
  if constexpr (!F32) {
    return *(const bf16x8*)((const u16*)base + off);
  } else {
    const float* p = (const float*)base + off;
    f32x4 a = *(const f32x4*)p;
    f32x4 b = *(const f32x4*)(p + 4);
    bf16x8 r;
    r[0] = (short)f2bf(a[0]); r[1] = (short)f2bf(a[1]);
    r[2] = (short)f2bf(a[2]); r[3] = (short)f2bf(a[3]);
    r[4] = (short)f2bf(b[0]); r[5] = (short)f2bf(b[1]);
    r[6] = (short)f2bf(b[2]); r[7] = (short)f2bf(b[3]);
    return r;
  }
}

// C = A[4096,1024] @ W[1024,1024]^T. MODE 0: row-major store (bf16 or f32 per O32).
// MODE 1: V-transpose store Vt[((b*16+h)*64+d)*2048 + s], always bf16.
template <int A32, int W32, int MODE, int O32>
DEVI void gemm_core(u16* sA, u16* sB, const void* A, const void* W, void* C) {
  constexpr int K = 1024, N = 1024;
  const int tid = threadIdx.x;
  const int lane = tid & 63;
  const int wave = tid >> 6;
  const int tileM = blockIdx.y * 128;
  const int tileN = blockIdx.x * 128;
  const int wr = (wave >> 1) * 64;
  const int wc = (wave & 1) * 64;
  const int lr = lane & 15;
  const int lg = lane >> 4;

  f32x4 acc[4][4] = {};

  const int e0 = tid * 8;
  const int e1 = 2048 + tid * 8;
  const int r0 = e0 >> 5, c0 = e0 & 31;
  const int r1 = e1 >> 5, c1 = e1 & 31;

  for (int k0 = 0; k0 < K; k0 += 32) {
    bf16x8 va0 = lda8<A32>(A, (size_t)(tileM + r0) * K + c0 + k0);
    bf16x8 va1 = lda8<A32>(A, (size_t)(tileM + r1) * K + c1 + k0);
    bf16x8 vb0 = lda8<W32>(W, (size_t)(tileN + r0) * K + c0 + k0);
    bf16x8 vb1 = lda8<W32>(W, (size_t)(tileN + r1) * K + c1 + k0);
    __syncthreads();
    *(bf16x8*)(sA + e0) = va0;
    *(bf16x8*)(sA + e1) = va1;
    *(bf16x8*)(sB + e0) = vb0;
    *(bf16x8*)(sB + e1) = vb1;
    __syncthreads();
    bf16x8 af[4], bfr[4];
#pragma unroll
    for (int m = 0; m < 4; ++m)
      af[m] = *(const bf16x8*)(sA + (wr + m * 16 + lr) * 32 + lg * 8);
#pragma unroll
    for (int n = 0; n < 4; ++n)
      bfr[n] = *(const bf16x8*)(sB + (wc + n * 16 + lr) * 32 + lg * 8);
#pragma unroll
    for (int m = 0; m < 4; ++m)
#pragma unroll
      for (int n = 0; n < 4; ++n)
        acc[m][n] = __builtin_amdgcn_mfma_f32_16x16x32_bf16(af[m], bfr[n], acc[m][n], 0, 0, 0);
  }

  if constexpr (MODE == 0) {
#pragma unroll
    for (int m = 0; m < 4; ++m) {
      const int row0 = tileM + wr + m * 16 + lg * 4;
#pragma unroll
      for (int n = 0; n < 4; ++n) {
        const int col = tileN + wc + n * 16 + lr;
#pragma unroll
        for (int j = 0; j < 4; ++j) {
          if constexpr (O32)
            ((float*)C)[(size_t)(row0 + j) * N + col] = acc[m][n][j];
          else
            ((u16*)C)[(size_t)(row0 + j) * N + col] = f2bf(acc[m][n][j]);
        }
      }
    }
  } else {
    u16* Cv = (u16*)C;
#pragma unroll
    for (int m = 0; m < 4; ++m) {
      const int row0 = tileM + wr + m * 16 + lg * 4;
      const int b = row0 >> 11, s0 = row0 & 2047;
#pragma unroll
      for (int n = 0; n < 4; ++n) {
        const int col = tileN + wc + n * 16 + lr;
        s16x4 pk;
#pragma unroll
        for (int j = 0; j < 4; ++j) pk[j] = (short)f2bf(acc[m][n][j]);
        *(s16x4*)(Cv + ((size_t)(col + (b << 10)) << 11) + s0) = pk;  // 4 consecutive s
      }
    }
  }
}

template <int IN32>
__global__ void __launch_bounds__(256)
gemm_qkv(const void* __restrict__ q, const void* __restrict__ wq, u16* __restrict__ Qp,
         const void* __restrict__ k, const void* __restrict__ wk, u16* __restrict__ Kp,
         const void* __restrict__ v, const void* __restrict__ wv, u16* __restrict__ Vt) {
  __shared__ u16 sA[128 * 32];
  __shared__ u16 sB[128 * 32];
  if (blockIdx.z == 0)      gemm_core<IN32, IN32, 0, 0>(sA, sB, q, wq, Qp);
  else if (blockIdx.z == 1) gemm_core<IN32, IN32, 0, 0>(sA, sB, k, wk, Kp);
  else                      gemm_core<IN32, IN32, 1, 0>(sA, sB, v, wv, Vt);
}

template <int W32, int O32>
__global__ void __launch_bounds__(256)
gemm_out(const u16* __restrict__ A, const void* __restrict__ W, void* __restrict__ C) {
  __shared__ u16 sA[128 * 32];
  __shared__ u16 sB[128 * 32];
  gemm_core<0, W32, 0, O32>(sA, sB, A, W, C);
}

// ---------------- Flash attention, causal, swapped-QK^T in-register softmax ----------
// One wave per 16-row q-tile. Lane (lr,lg): q-row = q0+lr (scores), keys in-register.
// S^T = mfma(K, Q): C col=lr -> q, row=lg*4+j -> key. P stays in lane as PV A-frag via
// matched k-permutation on the V B-frag. Defer-max rescale (log2-domain THR=11.5).

#define SCL 0.18033688011112042f  /* 0.125 * log2(e) */

template <bool MASKED>
DEVI void attn_step(int kt, int q0, int lr, int lg,
                    const u16* __restrict__ Kb, const u16* __restrict__ Vb,
                    bf16x8 qf0, bf16x8 qf1,
                    f32x4 (&o)[4], float& mr, float& ls) {
  // K A-frags: row=lr -> key kt(+16)+lr, k=lg*8+e -> dh
  const u16* K0 = Kb + (size_t)(kt + lr) * 1024 + lg * 8;
  const u16* K1 = K0 + 16 * 1024;
  const bf16x8 kf00 = *(const bf16x8*)(K0);
  const bf16x8 kf01 = *(const bf16x8*)(K0 + 32);
  const bf16x8 kf10 = *(const bf16x8*)(K1);
  const bf16x8 kf11 = *(const bf16x8*)(K1 + 32);

  const f32x4 z = {};
  f32x4 s0 = __builtin_amdgcn_mfma_f32_16x16x32_bf16(kf00, qf0, z, 0, 0, 0);
  s0 = __builtin_amdgcn_mfma_f32_16x16x32_bf16(kf01, qf1, s0, 0, 0, 0);
  f32x4 s1 = __builtin_amdgcn_mfma_f32_16x16x32_bf16(kf10, qf0, z, 0, 0, 0);
  s1 = __builtin_amdgcn_mfma_f32_16x16x32_bf16(kf11, qf1, s1, 0, 0, 0);

  float p[8];
  if constexpr (MASKED) {
    const int qrow = q0 + lr;
#pragma unroll
    for (int j = 0; j < 4; ++j) {
      p[j]     = (kt + lg * 4 + j      > qrow) ? -INFINITY : s0[j] * SCL;
      p[4 + j] = (kt + 16 + lg * 4 + j > qrow) ? -INFINITY : s1[j] * SCL;
    }
  } else {
#pragma unroll
    for (int j = 0; j < 4; ++j) { p[j] = s0[j] * SCL; p[4 + j] = s1[j] * SCL; }
  }

  // row max: in-lane 8 + cross-replica (xor16, xor32)
  float tm = fmaxf(fmaxf(fmaxf(p[0], p[1]), fmaxf(p[2], p[3])),
                   fmaxf(fmaxf(p[4], p[5]), fmaxf(p[6], p[7])));
  tm = fmaxf(tm, __shfl_xor(tm, 16));
  tm = fmaxf(tm, __shfl_xor(tm, 32));

  if (!__all(tm <= mr + 11.5f)) {      // rescale needed (always on first tile)
    const float mn = fmaxf(mr, tm);
    const float fac = exp2f(mr - mn);  // first tile: exp2(-inf) = 0
    mr = mn;
    ls *= fac;
#pragma unroll
    for (int j = 0; j < 4; ++j) {
      const float fj = __shfl(fac, lg * 4 + j);
#pragma unroll
      for (int d = 0; d < 4; ++d) o[d][j] *= fj;
    }
  }

#pragma unroll
  for (int i = 0; i < 8; ++i) p[i] = exp2f(p[i] - mr);
  float ts = ((p[0] + p[1]) + (p[2] + p[3])) + ((p[4] + p[5]) + (p[6] + p[7]));
  ts += __shfl_xor(ts, 16);
  ts += __shfl_xor(ts, 32);
  ls += ts;

  // pack P -> A-frag (k-slot (lg,e): e<4 -> key kt+lg*4+e, e>=4 -> kt+16+lg*4+(e-4))
  bf16x8 pa;
#pragma unroll
  for (int i = 0; i < 8; ++i) pa[i] = (short)f2bf(p[i]);

  // PV with matched permutation on V: B slot (lg,e) = V[key sigma][dh=16d+lr]
#pragma unroll
  for (int d = 0; d < 4; ++d) {
    const u16* vp = Vb + (size_t)(16 * d + lr) * 2048 + kt + lg * 4;
    const s16x4 v0 = *(const s16x4*)(vp);
    const s16x4 v1 = *(const s16x4*)(vp + 16);
    bf16x8 vf;
    vf[0] = v0[0]; vf[1] = v0[1]; vf[2] = v0[2]; vf[3] = v0[3];
    vf[4] = v1[0]; vf[5] = v1[1]; vf[6] = v1[2]; vf[7] = v1[3];
    o[d] = __builtin_amdgcn_mfma_f32_16x16x32_bf16(pa, vf, o[d], 0, 0, 0);
  }
}

__global__ void __launch_bounds__(256)
attn_kernel(const u16* __restrict__ Qp, const u16* __restrict__ Kp,
            const u16* __restrict__ Vt, u16* __restrict__ AO) {
  const int tid = threadIdx.x;
  const int lane = tid & 63;
  const int wave = tid >> 6;
  const int lr = lane & 15;
  const int lg = lane >> 4;
  const int bh = blockIdx.y;
  const int b = bh >> 4;
  const int h = bh & 15;
  // balance causal work: wave-tile = wave*32 + blockIdx.x (per-block iters ~flat)
  const int tile = wave * 32 + blockIdx.x;  // 0..127
  const int q0 = tile * 16;

  // Q B-frags: col=lr -> q-row q0+lr, k=lg*8+e -> dh (two 32-dh chunks)
  const u16* Qb = Qp + ((size_t)(b * 2048 + q0) << 10) + h * 64;
  const bf16x8 qf0 = *(const bf16x8*)(Qb + lr * 1024 + lg * 8);
  const bf16x8 qf1 = *(const bf16x8*)(Qb + lr * 1024 + 32 + lg * 8);

  const u16* Kb = Kp + ((size_t)(b * 2048) << 10) + h * 64;
  const u16* Vb = Vt + ((size_t)(bh * 64) << 11);  // [dh][s], stride 2048

  f32x4 o[4] = {};
  float mr = -INFINITY, ls = 0.f;

  const int kt_last = ((q0 + 15) >> 5) << 5;  // only tile needing causal mask
  for (int kt = 0; kt < kt_last; kt += 32)
    attn_step<false>(kt, q0, lr, lg, Kb, Vb, qf0, qf1, o, mr, ls);
  attn_step<true>(kt_last, q0, lr, lg, Kb, Vb, qf0, qf1, o, mr, ls);

  // normalize: ls lives in lr-space; o rows are lg*4+j
  const size_t orow = (size_t)(b * 2048 + q0 + lg * 4);
#pragma unroll
  for (int j = 0; j < 4; ++j) {
    const float inv = 1.0f / __shfl(ls, lg * 4 + j);
#pragma unroll
    for (int d = 0; d < 4; ++d)
      AO[(orow + j) * 1024 + h * 64 + 16 * d + lr] = f2bf(o[d][j] * inv);
  }
}

// Host-side bytes/element detection (capture-safe pure host queries).
static int bytes_per_elem(void* p, long long n, void* pnext) {
  if (pnext) {
    ptrdiff_t d = (char*)pnext - (char*)p;
    if (d == n * 2) return 2;
    if (d == n * 4) return 4;
  }
  size_t sz = 0;
  if (hipMemPtrGetInfo(p, &sz) == hipSuccess && sz >= (size_t)(n * 2)) {
    if (sz < (size_t)(n * 4)) return 2;
    if (sz <= (size_t)(n * 8)) return 4;
  }
  return 4;  // default fp32 (empirically correct for this harness)
}

extern "C" void kernel_launch(void* const* d_in, const int* in_sizes, int n_in,
                              void* d_out, int out_size, void* d_ws, size_t ws_size,
                              hipStream_t stream) {
  void* q  = d_in[0];
  void* k  = d_in[1];
  void* v  = d_in[2];
  // d_in[3] = causal tril mask (int32) -- hardcoded in attn_kernel
  void* wq = d_in[4];
  void* wk = d_in[5];
  void* wv = d_in[6];
  void* wo = d_in[7];

  const int in32 = bytes_per_elem(q, in_sizes[0], k) == 4;
  const int w32  = bytes_per_elem(wq, in_sizes[4], wk) == 4;
  const int o32  = bytes_per_elem(d_out, out_size, nullptr) == 4;

  const size_t SZ = (size_t)4096 * 1024;
  u16* Qp = (u16*)d_ws;        // [B,S,D] bf16
  u16* Kp = Qp + SZ;           // [B,S,D] bf16
  u16* Vt = (u16*)d_out;       // [B,H,DH,S] bf16 scratch; overwritten by gemm_out
  u16* AO = Qp;                // attn out aliases Qp (disjoint per-block elements)

  if (in32)
    gemm_qkv<1><<<dim3(8, 32, 3), 256, 0, stream>>>(q, wq, Qp, k, wk, Kp, v, wv, Vt);
  else
    gemm_qkv<0><<<dim3(8, 32, 3), 256, 0, stream>>>(q, wq, Qp, k, wk, Kp, v, wv, Vt);

  attn_kernel<<<dim3(32, 32), 256, 0, stream>>>(Qp, Kp, Vt, AO);

  if (w32) {
    if (o32) gemm_out<1, 1><<<dim3(8, 32), 256, 0, stream>>>(AO, wo, d_out);
    else     gemm_out<1, 0><<<dim3(8, 32), 256, 0, stream>>>(AO, wo, d_out);
  } else {
    if (o32) gemm_out<0, 1><<<dim3(8, 32), 256, 0, stream>>>(AO, wo, d_out);
    else     gemm_out<0, 0><<<dim3(8, 32), 256, 0, stream>>>(AO, wo, d_out);
  }
}

// Round 4
// 284.003 us; speedup vs baseline: 1.1939x; 1.1161x over previous
//
#include <hip/hip_runtime.h>
#include <hip/hip_bf16.h>

// B=2, S=2048, D=1024, H=16, DH=64. out = softmax(mask(QK^T/8)) V @ Wo^T, Q=x@Wq^T etc.
// Inputs fp32 (detected at launch; bf16 fallback kept). Internal: bf16 MFMA, fp32 accum.

typedef unsigned short u16;
typedef __attribute__((ext_vector_type(8))) short bf16x8;  // 8 bf16 = 4 VGPR
typedef __attribute__((ext_vector_type(4))) float f32x4;   // MFMA C/D frag
typedef __attribute__((ext_vector_type(4))) short s16x4;

#define DEVI static __device__ __forceinline__

DEVI u16 f2bf(float f) {
  __hip_bfloat16 h = __float2bfloat16(f);  // HW RNE; pairs into v_cvt_pk_bf16_f32
  union { __hip_bfloat16 h; u16 u; } c; c.h = h;
  return c.u;
}

template <int F32>
DEVI bf16x8 lda8(const void* base, size_t off) {
  if constexpr (!F32) {
    return *(const bf16x8*)((const u16*)base + off);
  } else {
    const float* p = (const float*)base + off;
    f32x4 a = *(const f32x4*)p;
    f32x4 b = *(const f32x4*)(p + 4);
    bf16x8 r;
    r[0] = (short)f2bf(a[0]); r[1] = (short)f2bf(a[1]);
    r[2] = (short)f2bf(a[2]); r[3] = (short)f2bf(a[3]);
    r[4] = (short)f2bf(b[0]); r[5] = (short)f2bf(b[1]);
    r[6] = (short)f2bf(b[2]); r[7] = (short)f2bf(b[3]);
    return r;
  }
}

// C = A[4096,1024] @ W[1024,1024]^T. MODE 0: row-major store (bf16 or f32 per O32).
// MODE 1: V-transpose store Vt[((b*16+h)*64+d)*2048 + s], always bf16.
template <int A32, int W32, int MODE, int O32>
DEVI void gemm_core(u16* sA, u16* sB, const void* A, const void* W, void* C) {
  constexpr int K = 1024, N = 1024;
  const int tid = threadIdx.x;
  const int lane = tid & 63;
  const int wave = tid >> 6;
  const int tileM = blockIdx.y * 128;
  const int tileN = blockIdx.x * 128;
  const int wr = (wave >> 1) * 64;
  const int wc = (wave & 1) * 64;
  const int lr = lane & 15;
  const int lg = lane >> 4;

  f32x4 acc[4][4] = {};

  const int e0 = tid * 8;
  const int e1 = 2048 + tid * 8;
  const int r0 = e0 >> 5, c0 = e0 & 31;
  const int r1 = e1 >> 5, c1 = e1 & 31;

  for (int k0 = 0; k0 < K; k0 += 32) {
    bf16x8 va0 = lda8<A32>(A, (size_t)(tileM + r0) * K + c0 + k0);
    bf16x8 va1 = lda8<A32>(A, (size_t)(tileM + r1) * K + c1 + k0);
    bf16x8 vb0 = lda8<W32>(W, (size_t)(tileN + r0) * K + c0 + k0);
    bf16x8 vb1 = lda8<W32>(W, (size_t)(tileN + r1) * K + c1 + k0);
    __syncthreads();
    *(bf16x8*)(sA + e0) = va0;
    *(bf16x8*)(sA + e1) = va1;
    *(bf16x8*)(sB + e0) = vb0;
    *(bf16x8*)(sB + e1) = vb1;
    __syncthreads();
    bf16x8 af[4], bfr[4];
#pragma unroll
    for (int m = 0; m < 4; ++m)
      af[m] = *(const bf16x8*)(sA + (wr + m * 16 + lr) * 32 + lg * 8);
#pragma unroll
    for (int n = 0; n < 4; ++n)
      bfr[n] = *(const bf16x8*)(sB + (wc + n * 16 + lr) * 32 + lg * 8);
#pragma unroll
    for (int m = 0; m < 4; ++m)
#pragma unroll
      for (int n = 0; n < 4; ++n)
        acc[m][n] = __builtin_amdgcn_mfma_f32_16x16x32_bf16(af[m], bfr[n], acc[m][n], 0, 0, 0);
  }

  if constexpr (MODE == 0) {
#pragma unroll
    for (int m = 0; m < 4; ++m) {
      const int row0 = tileM + wr + m * 16 + lg * 4;
#pragma unroll
      for (int n = 0; n < 4; ++n) {
        const int col = tileN + wc + n * 16 + lr;
#pragma unroll
        for (int j = 0; j < 4; ++j) {
          if constexpr (O32)
            ((float*)C)[(size_t)(row0 + j) * N + col] = acc[m][n][j];
          else
            ((u16*)C)[(size_t)(row0 + j) * N + col] = f2bf(acc[m][n][j]);
        }
      }
    }
  } else {
    u16* Cv = (u16*)C;
#pragma unroll
    for (int m = 0; m < 4; ++m) {
      const int row0 = tileM + wr + m * 16 + lg * 4;
      const int b = row0 >> 11, s0 = row0 & 2047;
#pragma unroll
      for (int n = 0; n < 4; ++n) {
        const int col = tileN + wc + n * 16 + lr;
        s16x4 pk;
#pragma unroll
        for (int j = 0; j < 4; ++j) pk[j] = (short)f2bf(acc[m][n][j]);
        *(s16x4*)(Cv + ((size_t)(col + (b << 10)) << 11) + s0) = pk;  // 4 consecutive s
      }
    }
  }
}

template <int IN32>
__global__ void __launch_bounds__(256)
gemm_qkv(const void* __restrict__ q, const void* __restrict__ wq, u16* __restrict__ Qp,
         const void* __restrict__ k, const void* __restrict__ wk, u16* __restrict__ Kp,
         const void* __restrict__ v, const void* __restrict__ wv, u16* __restrict__ Vt) {
  __shared__ u16 sA[128 * 32];
  __shared__ u16 sB[128 * 32];
  if (blockIdx.z == 0)      gemm_core<IN32, IN32, 0, 0>(sA, sB, q, wq, Qp);
  else if (blockIdx.z == 1) gemm_core<IN32, IN32, 0, 0>(sA, sB, k, wk, Kp);
  else                      gemm_core<IN32, IN32, 1, 0>(sA, sB, v, wv, Vt);
}

template <int W32, int O32>
__global__ void __launch_bounds__(256)
gemm_out(const u16* __restrict__ A, const void* __restrict__ W, void* __restrict__ C) {
  __shared__ u16 sA[128 * 32];
  __shared__ u16 sB[128 * 32];
  gemm_core<0, W32, 0, O32>(sA, sB, A, W, C);
}

// ---------------- Flash attention: swapped-QK^T, in-register softmax, ----------------
// ---------------- register-prefetch pipeline, XCD-local (b,h) mapping   ----------------
// Wave handles 16 q-rows. Lane (lr,lg): q-row=q0+lr; keys kt+{lg*4+j, 16+lg*4+j} in regs.

#define SCL 0.18033688011112042f  /* 0.125 * log2(e) */

DEVI void loadK(bf16x8 (&kf)[4], const u16* Kb, int kt, int lr, int lg) {
  const u16* K0 = Kb + (size_t)(kt + lr) * 1024 + lg * 8;
  const u16* K1 = K0 + 16 * 1024;
  kf[0] = *(const bf16x8*)(K0);
  kf[1] = *(const bf16x8*)(K0 + 32);
  kf[2] = *(const bf16x8*)(K1);
  kf[3] = *(const bf16x8*)(K1 + 32);
}

DEVI void loadV(bf16x8 (&vf)[4], const u16* Vb, int kt, int lr, int lg) {
#pragma unroll
  for (int d = 0; d < 4; ++d) {
    const u16* vp = Vb + (size_t)(16 * d + lr) * 2048 + kt + lg * 4;
    const s16x4 v0 = *(const s16x4*)(vp);
    const s16x4 v1 = *(const s16x4*)(vp + 16);
    vf[d][0] = v0[0]; vf[d][1] = v0[1]; vf[d][2] = v0[2]; vf[d][3] = v0[3];
    vf[d][4] = v1[0]; vf[d][5] = v1[1]; vf[d][6] = v1[2]; vf[d][7] = v1[3];
  }
}

DEVI void attn_compute(const bf16x8 (&kf)[4], const bf16x8 (&vf)[4],
                       bf16x8 qf0, bf16x8 qf1, int kt, int q0, int lr, int lg,
                       f32x4 (&o)[4], float& mr, float& ls, bool masked) {
  const f32x4 z = {};
  f32x4 s0 = __builtin_amdgcn_mfma_f32_16x16x32_bf16(kf[0], qf0, z, 0, 0, 0);
  s0 = __builtin_amdgcn_mfma_f32_16x16x32_bf16(kf[1], qf1, s0, 0, 0, 0);
  f32x4 s1 = __builtin_amdgcn_mfma_f32_16x16x32_bf16(kf[2], qf0, z, 0, 0, 0);
  s1 = __builtin_amdgcn_mfma_f32_16x16x32_bf16(kf[3], qf1, s1, 0, 0, 0);

  float p[8];
#pragma unroll
  for (int j = 0; j < 4; ++j) { p[j] = s0[j] * SCL; p[4 + j] = s1[j] * SCL; }
  if (masked) {  // wave-uniform branch (all lanes same kt)
    const int qrow = q0 + lr;
#pragma unroll
    for (int j = 0; j < 4; ++j) {
      if (kt + lg * 4 + j > qrow)      p[j] = -INFINITY;
      if (kt + 16 + lg * 4 + j > qrow) p[4 + j] = -INFINITY;
    }
  }

  float tm = fmaxf(fmaxf(fmaxf(p[0], p[1]), fmaxf(p[2], p[3])),
                   fmaxf(fmaxf(p[4], p[5]), fmaxf(p[6], p[7])));
  tm = fmaxf(tm, __shfl_xor(tm, 16));
  tm = fmaxf(tm, __shfl_xor(tm, 32));

  if (!__all(tm <= mr + 11.5f)) {      // defer-max (always taken on first tile)
    const float mn = fmaxf(mr, tm);
    const float fac = exp2f(mr - mn);
    mr = mn;
    ls *= fac;
#pragma unroll
    for (int j = 0; j < 4; ++j) {
      const float fj = __shfl(fac, lg * 4 + j);
#pragma unroll
      for (int d = 0; d < 4; ++d) o[d][j] *= fj;
    }
  }

#pragma unroll
  for (int i = 0; i < 8; ++i) p[i] = exp2f(p[i] - mr);
  float ts = ((p[0] + p[1]) + (p[2] + p[3])) + ((p[4] + p[5]) + (p[6] + p[7]));
  ts += __shfl_xor(ts, 16);
  ts += __shfl_xor(ts, 32);
  ls += ts;

  bf16x8 pa;
#pragma unroll
  for (int i = 0; i < 8; ++i) pa[i] = (short)f2bf(p[i]);

#pragma unroll
  for (int d = 0; d < 4; ++d)
    o[d] = __builtin_amdgcn_mfma_f32_16x16x32_bf16(pa, vf[d], o[d], 0, 0, 0);
}

__global__ void __launch_bounds__(256, 4)
attn_kernel(const u16* __restrict__ Qp, const u16* __restrict__ Kp,
            const u16* __restrict__ Vt, u16* __restrict__ AO) {
  const int tid = threadIdx.x;
  const int lane = tid & 63;
  const int wave = tid >> 6;
  const int lr = lane & 15;
  const int lg = lane >> 4;

  // XCD-local mapping: id%8 = XCD (round-robin dispatch). Each XCD owns 4 (b,h)
  // pairs -> per-XCD K/V working set 2 MB < 4 MB L2.
  const int id = blockIdx.x;          // 0..1023
  const int xcd = id & 7;
  const int slot = id >> 3;           // 0..127
  const int bh = xcd * 4 + (slot & 3);
  const int xpos = slot >> 2;         // 0..31
  const int b = bh >> 4;
  const int h = bh & 15;
  const int tile = wave * 32 + xpos;  // causal load balance across waves
  const int q0 = tile * 16;

  const u16* Qb = Qp + ((size_t)(b * 2048 + q0) << 10) + h * 64;
  const bf16x8 qf0 = *(const bf16x8*)(Qb + lr * 1024 + lg * 8);
  const bf16x8 qf1 = *(const bf16x8*)(Qb + lr * 1024 + 32 + lg * 8);

  const u16* Kb = Kp + ((size_t)(b * 2048) << 10) + h * 64;
  const u16* Vb = Vt + ((size_t)(bh * 64) << 11);  // [dh][s], stride 2048

  f32x4 o[4] = {};
  float mr = -INFINITY, ls = 0.f;

  const int n = tile / 2 + 1;  // number of 32-key tiles (last one masked)
  bf16x8 ka[4], kb_[4], vb[4];

  loadK(ka, Kb, 0, lr, lg);
  int t = 0;
  while (true) {
    {  // step with ka
      const bool last = (t == n - 1);
      loadV(vb, Vb, t * 32, lr, lg);
      if (!last) loadK(kb_, Kb, (t + 1) * 32, lr, lg);
      attn_compute(ka, vb, qf0, qf1, t * 32, q0, lr, lg, o, mr, ls, last);
      if (last) break;
      ++t;
    }
    {  // step with kb_
      const bool last = (t == n - 1);
      loadV(vb, Vb, t * 32, lr, lg);
      if (!last) loadK(ka, Kb, (t + 1) * 32, lr, lg);
      attn_compute(kb_, vb, qf0, qf1, t * 32, q0, lr, lg, o, mr, ls, last);
      if (last) break;
      ++t;
    }
  }

  const size_t orow = (size_t)(b * 2048 + q0 + lg * 4);
#pragma unroll
  for (int j = 0; j < 4; ++j) {
    const float inv = 1.0f / __shfl(ls, lg * 4 + j);
#pragma unroll
    for (int d = 0; d < 4; ++d)
      AO[(orow + j) * 1024 + h * 64 + 16 * d + lr] = f2bf(o[d][j] * inv);
  }
}

// Host-side bytes/element detection (capture-safe pure host queries).
static int bytes_per_elem(void* p, long long n, void* pnext) {
  if (pnext) {
    ptrdiff_t d = (char*)pnext - (char*)p;
    if (d == n * 2) return 2;
    if (d == n * 4) return 4;
  }
  size_t sz = 0;
  if (hipMemPtrGetInfo(p, &sz) == hipSuccess && sz >= (size_t)(n * 2)) {
    if (sz < (size_t)(n * 4)) return 2;
    if (sz <= (size_t)(n * 8)) return 4;
  }
  return 4;  // default fp32 (empirically correct for this harness)
}

extern "C" void kernel_launch(void* const* d_in, const int* in_sizes, int n_in,
                              void* d_out, int out_size, void* d_ws, size_t ws_size,
                              hipStream_t stream) {
  void* q  = d_in[0];
  void* k  = d_in[1];
  void* v  = d_in[2];
  // d_in[3] = causal tril mask (int32) -- hardcoded in attn_kernel
  void* wq = d_in[4];
  void* wk = d_in[5];
  void* wv = d_in[6];
  void* wo = d_in[7];

  const int in32 = bytes_per_elem(q, in_sizes[0], k) == 4;
  const int w32  = bytes_per_elem(wq, in_sizes[4], wk) == 4;
  const int o32  = bytes_per_elem(d_out, out_size, nullptr) == 4;

  const size_t SZ = (size_t)4096 * 1024;
  u16* Qp = (u16*)d_ws;        // [B,S,D] bf16
  u16* Kp = Qp + SZ;           // [B,S,D] bf16
  u16* Vt = (u16*)d_out;       // [B,H,DH,S] bf16 scratch; overwritten by gemm_out
  u16* AO = Qp;                // attn out aliases Qp (disjoint per-block elements)

  if (in32)
    gemm_qkv<1><<<dim3(8, 32, 3), 256, 0, stream>>>(q, wq, Qp, k, wk, Kp, v, wv, Vt);
  else
    gemm_qkv<0><<<dim3(8, 32, 3), 256, 0, stream>>>(q, wq, Qp, k, wk, Kp, v, wv, Vt);

  attn_kernel<<<dim3(1024), 256, 0, stream>>>(Qp, Kp, Vt, AO);

  if (w32) {
    if (o32) gemm_out<1, 1><<<dim3(8, 32), 256, 0, stream>>>(AO, wo, d_out);
    else     gemm_out<1, 0><<<dim3(8, 32), 256, 0, stream>>>(AO, wo, d_out);
  } else {
    if (o32) gemm_out<0, 1><<<dim3(8, 32), 256, 0, stream>>>(AO, wo, d_out);
    else     gemm_out<0, 0><<<dim3(8, 32), 256, 0, stream>>>(AO, wo, d_out);
  }
}

// Round 5
// 160.005 us; speedup vs baseline: 2.1191x; 1.7750x over previous
//
#include <hip/hip_runtime.h>
#include <hip/hip_bf16.h>

// B=2, S=2048, D=1024, H=16, DH=64. out = softmax(mask(QK^T/8)) V @ Wo^T, Q=x@Wq^T etc.
// fp32 inputs (detected at launch). Internal: bf16 MFMA, fp32 accum.
// ws (16MB): Qp token-major [B,S,D] + Kh head-major [B,H,S,DH].
// d_out lower 8MB: Vt transposed [B,H,DH,S] scratch (overwritten by final GEMM).
// AO aliases Qp (per-block element sets identical between read and write).

typedef unsigned short u16;
typedef __attribute__((ext_vector_type(8))) short bf16x8;  // 8 bf16 = 4 VGPR
typedef __attribute__((ext_vector_type(4))) float f32x4;   // MFMA C/D frag
typedef __attribute__((ext_vector_type(4))) short s16x4;

#define DEVI static __device__ __forceinline__

DEVI u16 f2bf(float f) {
  __hip_bfloat16 h = __float2bfloat16(f);
  union { __hip_bfloat16 h; u16 u; } c; c.h = h;
  return c.u;
}

template <int F32>
DEVI bf16x8 lda8(const void* base, size_t off) {
  if constexpr (!F32) {
    return *(const bf16x8*)((const u16*)base + off);
  } else {
    const float* p = (const float*)base + off;
    f32x4 a = *(const f32x4*)p;
    f32x4 b = *(const f32x4*)(p + 4);
    bf16x8 r;
    r[0] = (short)f2bf(a[0]); r[1] = (short)f2bf(a[1]);
    r[2] = (short)f2bf(a[2]); r[3] = (short)f2bf(a[3]);
    r[4] = (short)f2bf(b[0]); r[5] = (short)f2bf(b[1]);
    r[6] = (short)f2bf(b[2]); r[7] = (short)f2bf(b[3]);
    return r;
  }
}

// C = A[4096,1024] @ W[1024,1024]^T.
// MODE 0: token-major bf16/f32. MODE 1: V-transpose Vt[((b*16+h)*64+d)*2048+s].
// MODE 2: head-major Kh[((b*16+h)*2048+s)*64+dh].
template <int A32, int W32, int MODE, int O32>
DEVI void gemm_core(u16* sA, u16* sB, const void* A, const void* W, void* C) {
  constexpr int K = 1024, N = 1024;
  const int tid = threadIdx.x;
  const int lane = tid & 63;
  const int wave = tid >> 6;
  const int tileM = blockIdx.y * 128;
  const int tileN = blockIdx.x * 128;
  const int wr = (wave >> 1) * 64;
  const int wc = (wave & 1) * 64;
  const int lr = lane & 15;
  const int lg = lane >> 4;

  f32x4 acc[4][4] = {};

  const int e0 = tid * 8;
  const int e1 = 2048 + tid * 8;
  const int r0 = e0 >> 5, c0 = e0 & 31;
  const int r1 = e1 >> 5, c1 = e1 & 31;

  for (int k0 = 0; k0 < K; k0 += 32) {
    bf16x8 va0 = lda8<A32>(A, (size_t)(tileM + r0) * K + c0 + k0);
    bf16x8 va1 = lda8<A32>(A, (size_t)(tileM + r1) * K + c1 + k0);
    bf16x8 vb0 = lda8<W32>(W, (size_t)(tileN + r0) * K + c0 + k0);
    bf16x8 vb1 = lda8<W32>(W, (size_t)(tileN + r1) * K + c1 + k0);
    __syncthreads();
    *(bf16x8*)(sA + e0) = va0;
    *(bf16x8*)(sA + e1) = va1;
    *(bf16x8*)(sB + e0) = vb0;
    *(bf16x8*)(sB + e1) = vb1;
    __syncthreads();
    bf16x8 af[4], bfr[4];
#pragma unroll
    for (int m = 0; m < 4; ++m)
      af[m] = *(const bf16x8*)(sA + (wr + m * 16 + lr) * 32 + lg * 8);
#pragma unroll
    for (int n = 0; n < 4; ++n)
      bfr[n] = *(const bf16x8*)(sB + (wc + n * 16 + lr) * 32 + lg * 8);
#pragma unroll
    for (int m = 0; m < 4; ++m)
#pragma unroll
      for (int n = 0; n < 4; ++n)
        acc[m][n] = __builtin_amdgcn_mfma_f32_16x16x32_bf16(af[m], bfr[n], acc[m][n], 0, 0, 0);
  }

  if constexpr (MODE == 0) {
#pragma unroll
    for (int m = 0; m < 4; ++m) {
      const int row0 = tileM + wr + m * 16 + lg * 4;
#pragma unroll
      for (int n = 0; n < 4; ++n) {
        const int col = tileN + wc + n * 16 + lr;
#pragma unroll
        for (int j = 0; j < 4; ++j) {
          if constexpr (O32)
            ((float*)C)[(size_t)(row0 + j) * N + col] = acc[m][n][j];
          else
            ((u16*)C)[(size_t)(row0 + j) * N + col] = f2bf(acc[m][n][j]);
        }
      }
    }
  } else if constexpr (MODE == 1) {
    u16* Cv = (u16*)C;
#pragma unroll
    for (int m = 0; m < 4; ++m) {
      const int row0 = tileM + wr + m * 16 + lg * 4;
      const int bb = row0 >> 11, s0 = row0 & 2047;
#pragma unroll
      for (int n = 0; n < 4; ++n) {
        const int col = tileN + wc + n * 16 + lr;
        s16x4 pk;
#pragma unroll
        for (int j = 0; j < 4; ++j) pk[j] = (short)f2bf(acc[m][n][j]);
        *(s16x4*)(Cv + ((size_t)(col + (bb << 10)) << 11) + s0) = pk;
      }
    }
  } else {  // MODE 2: head-major
    u16* Cv = (u16*)C;
#pragma unroll
    for (int m = 0; m < 4; ++m) {
      const int row0 = tileM + wr + m * 16 + lg * 4;
      const int bb = row0 >> 11, s0 = row0 & 2047;
#pragma unroll
      for (int n = 0; n < 4; ++n) {
        const int col = tileN + wc + n * 16 + lr;
        const size_t base = ((size_t)((bb << 4) + (col >> 6)) * 2048 + s0) * 64 + (col & 63);
#pragma unroll
        for (int j = 0; j < 4; ++j)
          Cv[base + (size_t)j * 64] = f2bf(acc[m][n][j]);
      }
    }
  }
}

template <int IN32>
__global__ void __launch_bounds__(256)
gemm_qkv(const void* __restrict__ q, const void* __restrict__ wq, u16* __restrict__ Qp,
         const void* __restrict__ k, const void* __restrict__ wk, u16* __restrict__ Kh,
         const void* __restrict__ v, const void* __restrict__ wv, u16* __restrict__ Vt) {
  __shared__ u16 sA[128 * 32];
  __shared__ u16 sB[128 * 32];
  if (blockIdx.z == 0)      gemm_core<IN32, IN32, 0, 0>(sA, sB, q, wq, Qp);
  else if (blockIdx.z == 1) gemm_core<IN32, IN32, 2, 0>(sA, sB, k, wk, Kh);
  else                      gemm_core<IN32, IN32, 1, 0>(sA, sB, v, wv, Vt);
}

template <int W32, int O32>
__global__ void __launch_bounds__(256)
gemm_out(const u16* __restrict__ A, const void* __restrict__ W, void* __restrict__ C) {
  __shared__ u16 sA[128 * 32];
  __shared__ u16 sB[128 * 32];
  gemm_core<0, W32, 0, O32>(sA, sB, A, W, C);
}

// ---------------- Flash attention: block-cooperative LDS staging ----------------
// 128-thread blocks (2 waves), 32 q-rows (16/wave), 32-key tiles double-buffered in
// LDS. Causal balance: block x does bands x and 63-x (65 tiles total, uniform).
// K LDS tile [key 32][dh 64], granule(16B)-swizzle g' = g ^ (key&7).
// V LDS tile [dh 64][key 32], granule-swizzle g' = g ^ (dh&3).
// Staged via global_load_lds with inverse-swizzled SOURCE addresses (linear dest).

#define SCL 0.18033688011112042f  /* 0.125 * log2(e) */

DEVI void stage_klds(const u16* __restrict__ Kb, const u16* __restrict__ Vb,
                     u16* sKb, u16* sVb, int kt, int w, int lane) {
  const int kr = lane >> 3;                 // key row 0..7 (+8 for 2nd instr)
  const int kg = (lane & 7) ^ kr;           // source granule (dh/8)
  const u16* gk = Kb + (size_t)(kt + w * 16 + kr) * 64 + kg * 8;
  const int vr = lane >> 2;                 // dh row 0..15 (+16 for 2nd instr)
  const int vg = (lane & 3) ^ (vr & 3);     // source granule (key/8)
  const u16* gv = Vb + (size_t)(w * 32 + vr) * 2048 + kt + vg * 8;
  u16* dk = sKb + w * 1024;
  u16* dv = sVb + w * 1024;
  __builtin_amdgcn_global_load_lds((const __attribute__((address_space(1))) unsigned*)gk,
                                   (__attribute__((address_space(3))) unsigned*)dk, 16, 0, 0);
  __builtin_amdgcn_global_load_lds((const __attribute__((address_space(1))) unsigned*)(gk + 8 * 64),
                                   (__attribute__((address_space(3))) unsigned*)(dk + 512), 16, 0, 0);
  __builtin_amdgcn_global_load_lds((const __attribute__((address_space(1))) unsigned*)gv,
                                   (__attribute__((address_space(3))) unsigned*)dv, 16, 0, 0);
  __builtin_amdgcn_global_load_lds((const __attribute__((address_space(1))) unsigned*)(gv + (size_t)16 * 2048),
                                   (__attribute__((address_space(3))) unsigned*)(dv + 512), 16, 0, 0);
}

__global__ void __launch_bounds__(128, 4)
attn_kernel(const u16* Qp, const u16* __restrict__ Kh,
            const u16* __restrict__ Vt, u16* AO) {
  __shared__ __align__(16) u16 sK[2][2048];
  __shared__ __align__(16) u16 sV[2][2048];
  const int tid = threadIdx.x;
  const int lane = tid & 63;
  const int w = tid >> 6;          // 0..1
  const int lr = lane & 15;
  const int lg = lane >> 4;

  const int id = blockIdx.x;       // 0..1023
  const int xcd = id & 7;
  const int slot = id >> 3;        // 0..127
  const int bh = xcd * 4 + (slot & 3);
  const int x = slot >> 2;         // 0..31
  const int b = bh >> 4;
  const int h = bh & 15;

  const u16* Kb = Kh + (size_t)bh * 2048 * 64;
  const u16* Vb = Vt + (size_t)bh * 64 * 2048;

#pragma unroll 1
  for (int band = 0; band < 2; ++band) {
    const int r0 = 32 * (band ? x : (63 - x));
    const int qrow = r0 + w * 16 + lr;   // this lane's q-row
    const u16* Qw = Qp + ((size_t)(b * 2048 + qrow) << 10) + h * 64;
    const bf16x8 qf0 = *(const bf16x8*)(Qw + lg * 8);
    const bf16x8 qf1 = *(const bf16x8*)(Qw + 32 + lg * 8);

    f32x4 o[4] = {};
    float mr = -INFINITY, ls = 0.f;
    const int nt = (r0 >> 5) + 1;        // tiles; last one masked (for both waves)

    stage_klds(Kb, Vb, sK[0], sV[0], 0, w, lane);

#pragma unroll 1
    for (int t = 0; t < nt; ++t) {
      if (t + 1 < nt) {
        stage_klds(Kb, Vb, sK[(t + 1) & 1], sV[(t + 1) & 1], (t + 1) * 32, w, lane);
        asm volatile("s_waitcnt vmcnt(4)" ::: "memory");
      } else {
        asm volatile("s_waitcnt vmcnt(0)" ::: "memory");
      }
      asm volatile("s_barrier" ::: "memory");

      {
        const u16* sKb = sK[t & 1];
        const u16* sVb = sV[t & 1];
        const int sw = lr & 7;
        const bf16x8 kf0 = *(const bf16x8*)(sKb + lr * 64 + ((lg ^ sw) * 8));
        const bf16x8 kf1 = *(const bf16x8*)(sKb + lr * 64 + (((4 + lg) ^ sw) * 8));
        const bf16x8 kf2 = *(const bf16x8*)(sKb + (16 + lr) * 64 + ((lg ^ sw) * 8));
        const bf16x8 kf3 = *(const bf16x8*)(sKb + (16 + lr) * 64 + (((4 + lg) ^ sw) * 8));

        const f32x4 z = {};
        f32x4 s0 = __builtin_amdgcn_mfma_f32_16x16x32_bf16(kf0, qf0, z, 0, 0, 0);
        s0 = __builtin_amdgcn_mfma_f32_16x16x32_bf16(kf1, qf1, s0, 0, 0, 0);
        f32x4 s1 = __builtin_amdgcn_mfma_f32_16x16x32_bf16(kf2, qf0, z, 0, 0, 0);
        s1 = __builtin_amdgcn_mfma_f32_16x16x32_bf16(kf3, qf1, s1, 0, 0, 0);

        float p[8];
#pragma unroll
        for (int j = 0; j < 4; ++j) { p[j] = s0[j] * SCL; p[4 + j] = s1[j] * SCL; }
        if (t == nt - 1) {  // wave-uniform: only last tile needs the causal mask
          const int kt0 = t * 32;
#pragma unroll
          for (int j = 0; j < 4; ++j) {
            if (kt0 + lg * 4 + j > qrow)      p[j] = -INFINITY;
            if (kt0 + 16 + lg * 4 + j > qrow) p[4 + j] = -INFINITY;
          }
        }

        const float tm = fmaxf(fmaxf(fmaxf(p[0], p[1]), fmaxf(p[2], p[3])),
                               fmaxf(fmaxf(p[4], p[5]), fmaxf(p[6], p[7])));
        if (!__all(tm <= mr + 11.5f)) {   // rare (and first tile)
          float tr_ = fmaxf(tm, __shfl_xor(tm, 16));
          tr_ = fmaxf(tr_, __shfl_xor(tr_, 32));
          const float mn = fmaxf(mr, tr_);
          const float fac = exp2f(mr - mn);
          mr = mn;
          ls *= fac;
#pragma unroll
          for (int j = 0; j < 4; ++j) {
            const float fj = __shfl(fac, lg * 4 + j);
#pragma unroll
            for (int d = 0; d < 4; ++d) o[d][j] *= fj;
          }
        }

#pragma unroll
        for (int i = 0; i < 8; ++i) p[i] = exp2f(p[i] - mr);
        ls += ((p[0] + p[1]) + (p[2] + p[3])) + ((p[4] + p[5]) + (p[6] + p[7]));

        bf16x8 pa;
#pragma unroll
        for (int i = 0; i < 8; ++i) pa[i] = (short)f2bf(p[i]);

        const int s3 = lr & 3;
#pragma unroll
        for (int d = 0; d < 4; ++d) {
          const u16* vrow = sVb + (16 * d + lr) * 32;
          const s16x4 v0 = *(const s16x4*)(vrow + (((lg >> 1) ^ s3) * 8) + (lg & 1) * 4);
          const s16x4 v1 = *(const s16x4*)(vrow + ((((lg >> 1) + 2) ^ s3) * 8) + (lg & 1) * 4);
          bf16x8 vf;
          vf[0] = v0[0]; vf[1] = v0[1]; vf[2] = v0[2]; vf[3] = v0[3];
          vf[4] = v1[0]; vf[5] = v1[1]; vf[6] = v1[2]; vf[7] = v1[3];
          o[d] = __builtin_amdgcn_mfma_f32_16x16x32_bf16(pa, vf, o[d], 0, 0, 0);
        }
      }
      asm volatile("s_barrier" ::: "memory");
    }

    // finalize: reduce per-lane partial ls across the 4 replicas, then write
    float lt = ls + __shfl_xor(ls, 16);
    lt += __shfl_xor(lt, 32);
    const size_t orow = (size_t)(b * 2048 + r0 + w * 16 + lg * 4);
#pragma unroll
    for (int j = 0; j < 4; ++j) {
      const float inv = 1.0f / __shfl(lt, lg * 4 + j);
#pragma unroll
      for (int d = 0; d < 4; ++d)
        AO[(orow + j) * 1024 + h * 64 + 16 * d + lr] = f2bf(o[d][j] * inv);
    }
  }
}

// Host-side bytes/element detection (capture-safe pure host queries).
static int bytes_per_elem(void* p, long long n, void* pnext) {
  if (pnext) {
    ptrdiff_t d = (char*)pnext - (char*)p;
    if (d == n * 2) return 2;
    if (d == n * 4) return 4;
  }
  size_t sz = 0;
  if (hipMemPtrGetInfo(p, &sz) == hipSuccess && sz >= (size_t)(n * 2)) {
    if (sz < (size_t)(n * 4)) return 2;
    if (sz <= (size_t)(n * 8)) return 4;
  }
  return 4;
}

extern "C" void kernel_launch(void* const* d_in, const int* in_sizes, int n_in,
                              void* d_out, int out_size, void* d_ws, size_t ws_size,
                              hipStream_t stream) {
  void* q  = d_in[0];
  void* k  = d_in[1];
  void* v  = d_in[2];
  // d_in[3] = causal tril mask (int32) -- hardcoded in attn_kernel
  void* wq = d_in[4];
  void* wk = d_in[5];
  void* wv = d_in[6];
  void* wo = d_in[7];

  const int in32 = bytes_per_elem(q, in_sizes[0], k) == 4;
  const int w32  = bytes_per_elem(wq, in_sizes[4], wk) == 4;
  const int o32  = bytes_per_elem(d_out, out_size, nullptr) == 4;

  const size_t SZ = (size_t)4096 * 1024;
  u16* Qp = (u16*)d_ws;        // [B,S,D] token-major bf16
  u16* Kh = Qp + SZ;           // [B,H,S,DH] head-major bf16
  u16* Vt = (u16*)d_out;       // [B,H,DH,S] bf16 scratch; overwritten by gemm_out
  u16* AO = Qp;                // attn out aliases Qp (identical element sets per block)

  if (in32)
    gemm_qkv<1><<<dim3(8, 32, 3), 256, 0, stream>>>(q, wq, Qp, k, wk, Kh, v, wv, Vt);
  else
    gemm_qkv<0><<<dim3(8, 32, 3), 256, 0, stream>>>(q, wq, Qp, k, wk, Kh, v, wv, Vt);

  attn_kernel<<<dim3(1024), 128, 0, stream>>>(Qp, Kh, Vt, AO);

  if (w32) {
    if (o32) gemm_out<1, 1><<<dim3(8, 32), 256, 0, stream>>>(AO, wo, d_out);
    else     gemm_out<1, 0><<<dim3(8, 32), 256, 0, stream>>>(AO, wo, d_out);
  } else {
    if (o32) gemm_out<0, 1><<<dim3(8, 32), 256, 0, stream>>>(AO, wo, d_out);
    else     gemm_out<0, 0><<<dim3(8, 32), 256, 0, stream>>>(AO, wo, d_out);
  }
}

// Round 7
// 145.725 us; speedup vs baseline: 2.3268x; 1.0980x over previous
//
#include <hip/hip_runtime.h>
#include <hip/hip_bf16.h>

// B=2, S=2048, D=1024, H=16, DH=64. out = softmax(mask(QK^T/8)) V @ Wo^T, Q=x@Wq^T etc.
// fp32 inputs (detected at launch). Internal: bf16 MFMA, fp32 accum.
// ws (16MB): Qp token-major [B,S,D] + Kh head-major [B,H,S,DH].
// d_out lower 8MB: Vt transposed [B,H,DH,S] scratch (overwritten by final GEMM).
// AO aliases Qp (per-block element sets identical between read and write).

typedef unsigned short u16;
typedef __attribute__((ext_vector_type(8))) short bf16x8;  // 8 bf16 = 4 VGPR
typedef __attribute__((ext_vector_type(4))) float f32x4;   // MFMA C/D frag
typedef __attribute__((ext_vector_type(4))) short s16x4;

#define DEVI static __device__ __forceinline__

DEVI u16 f2bf(float f) {
  __hip_bfloat16 h = __float2bfloat16(f);
  union { __hip_bfloat16 h; u16 u; } c; c.h = h;
  return c.u;
}

template <int F32>
DEVI bf16x8 lda8(const void* base, size_t off) {
  if constexpr (!F32) {
    return *(const bf16x8*)((const u16*)base + off);
  } else {
    const float* p = (const float*)base + off;
    f32x4 a = *(const f32x4*)p;
    f32x4 b = *(const f32x4*)(p + 4);
    bf16x8 r;
    r[0] = (short)f2bf(a[0]); r[1] = (short)f2bf(a[1]);
    r[2] = (short)f2bf(a[2]); r[3] = (short)f2bf(a[3]);
    r[4] = (short)f2bf(b[0]); r[5] = (short)f2bf(b[1]);
    r[6] = (short)f2bf(b[2]); r[7] = (short)f2bf(b[3]);
    return r;
  }
}

// C = A[4096,1024] @ W[1024,1024]^T. Tile 128x256, 512 threads (8 waves, 64x64/wave).
// MODE 0: token-major bf16/f32. MODE 1: V-transpose Vt[((b*16+h)*64+d)*2048+s].
// MODE 2: head-major Kh[((b*16+h)*2048+s)*64+dh].
template <int A32, int W32, int MODE, int O32>
DEVI void gemm_core(u16* sA, u16* sB, const void* A, const void* W, void* C,
                    int tileM, int tileN) {
  constexpr int K = 1024, N = 1024;
  const int tid = threadIdx.x;          // 0..511
  const int lane = tid & 63;
  const int wave = tid >> 6;            // 0..7
  const int wr = (wave >> 2) * 64;      // M: {0,64}
  const int wc = (wave & 3) * 64;       // N: {0,64,128,192}
  const int lr = lane & 15;
  const int lg = lane >> 4;

  f32x4 acc[4][4] = {};

  const int ea = tid * 8;               // A: 128x32 = 4096 elems, one round
  const int ra = ea >> 5, ca = ea & 31;
  const int eb1 = 4096 + tid * 8;       // B: 256x32 = 8192 elems, two rounds
  const int rb1 = eb1 >> 5, cb1 = eb1 & 31;

  for (int k0 = 0; k0 < K; k0 += 32) {
    bf16x8 va  = lda8<A32>(A, (size_t)(tileM + ra) * K + ca + k0);
    bf16x8 vb0 = lda8<W32>(W, (size_t)(tileN + ra) * K + ca + k0);
    bf16x8 vb1 = lda8<W32>(W, (size_t)(tileN + rb1) * K + cb1 + k0);
    __syncthreads();
    *(bf16x8*)(sA + ea) = va;
    *(bf16x8*)(sB + ea) = vb0;
    *(bf16x8*)(sB + eb1) = vb1;
    __syncthreads();
    bf16x8 af[4], bfr[4];
#pragma unroll
    for (int m = 0; m < 4; ++m)
      af[m] = *(const bf16x8*)(sA + (wr + m * 16 + lr) * 32 + lg * 8);
#pragma unroll
    for (int n = 0; n < 4; ++n)
      bfr[n] = *(const bf16x8*)(sB + (wc + n * 16 + lr) * 32 + lg * 8);
#pragma unroll
    for (int m = 0; m < 4; ++m)
#pragma unroll
      for (int n = 0; n < 4; ++n)
        acc[m][n] = __builtin_amdgcn_mfma_f32_16x16x32_bf16(af[m], bfr[n], acc[m][n], 0, 0, 0);
  }

  if constexpr (MODE == 0) {
#pragma unroll
    for (int m = 0; m < 4; ++m) {
      const int row0 = tileM + wr + m * 16 + lg * 4;
#pragma unroll
      for (int n = 0; n < 4; ++n) {
        const int col = tileN + wc + n * 16 + lr;
#pragma unroll
        for (int j = 0; j < 4; ++j) {
          if constexpr (O32)
            ((float*)C)[(size_t)(row0 + j) * N + col] = acc[m][n][j];
          else
            ((u16*)C)[(size_t)(row0 + j) * N + col] = f2bf(acc[m][n][j]);
        }
      }
    }
  } else if constexpr (MODE == 1) {
    u16* Cv = (u16*)C;
#pragma unroll
    for (int m = 0; m < 4; ++m) {
      const int row0 = tileM + wr + m * 16 + lg * 4;
      const int bb = row0 >> 11, s0 = row0 & 2047;
#pragma unroll
      for (int n = 0; n < 4; ++n) {
        const int col = tileN + wc + n * 16 + lr;
        s16x4 pk;
#pragma unroll
        for (int j = 0; j < 4; ++j) pk[j] = (short)f2bf(acc[m][n][j]);
        *(s16x4*)(Cv + ((size_t)(col + (bb << 10)) << 11) + s0) = pk;
      }
    }
  } else {  // MODE 2: head-major
    u16* Cv = (u16*)C;
#pragma unroll
    for (int m = 0; m < 4; ++m) {
      const int row0 = tileM + wr + m * 16 + lg * 4;
      const int bb = row0 >> 11, s0 = row0 & 2047;
#pragma unroll
      for (int n = 0; n < 4; ++n) {
        const int col = tileN + wc + n * 16 + lr;
        const size_t base = ((size_t)((bb << 4) + (col >> 6)) * 2048 + s0) * 64 + (col & 63);
#pragma unroll
        for (int j = 0; j < 4; ++j)
          Cv[base + (size_t)j * 64] = f2bf(acc[m][n][j]);
      }
    }
  }
}

// XCD-local tile remap: XCD c owns M-panels [4c,4c+4) x all 4 N-tiles.
DEVI void tile_remap(int& tileM, int& tileN) {
  const int i = blockIdx.x + 4 * blockIdx.y;  // 0..127; XCD = i & 7 (id%8 round-robin)
  const int c = i & 7, s = i >> 3;            // s: 0..15
  tileM = (c * 4 + (s & 3)) * 128;
  tileN = (s >> 2) * 256;
}

template <int IN32>
__global__ void __launch_bounds__(512, 2)
gemm_qkv(const void* __restrict__ q, const void* __restrict__ wq, u16* __restrict__ Qp,
         const void* __restrict__ k, const void* __restrict__ wk, u16* __restrict__ Kh,
         const void* __restrict__ v, const void* __restrict__ wv, u16* __restrict__ Vt) {
  __shared__ u16 sA[128 * 32];
  __shared__ u16 sB[256 * 32];
  int tileM, tileN;
  tile_remap(tileM, tileN);
  if (blockIdx.z == 0)      gemm_core<IN32, IN32, 0, 0>(sA, sB, q, wq, Qp, tileM, tileN);
  else if (blockIdx.z == 1) gemm_core<IN32, IN32, 2, 0>(sA, sB, k, wk, Kh, tileM, tileN);
  else                      gemm_core<IN32, IN32, 1, 0>(sA, sB, v, wv, Vt, tileM, tileN);
}

template <int W32, int O32>
__global__ void __launch_bounds__(512, 2)
gemm_out(const u16* __restrict__ A, const void* __restrict__ W, void* __restrict__ C) {
  __shared__ u16 sA[128 * 32];
  __shared__ u16 sB[256 * 32];
  int tileM, tileN;
  tile_remap(tileM, tileN);
  gemm_core<0, W32, 0, O32>(sA, sB, A, W, C, tileM, tileN);
}

// ---------------- Flash attention: block-cooperative LDS staging ----------------
// 128-thread blocks (2 waves), 32 q-rows (16/wave), 32-key tiles QUAD-buffered in
// LDS, depth-2 prefetch, ONE barrier per tile.
// Race-freedom: stage(t+2) targets (t+2)&3; concurrent computes are only {t-1, t}
// (slowest wave passed barrier(t-1)): (t+2)-(t-1)=3, (t+2)-t=2, both !=0 mod 4.
// Reused buffer (t-2)&3 was last read by compute(t-2), finished by all waves before
// barrier(t-1). Staleness: per-wave vmcnt(8) drains own stage(t) BEFORE the barrier;
// barrier joins -> all waves' stage(t) complete.
// Causal balance: block x does bands x and 63-x (65 tiles total, uniform).
// K LDS tile [key 32][dh 64], granule(16B)-swizzle g' = g ^ (key&7).
// V LDS tile [dh 64][key 32], granule-swizzle g' = g ^ (dh&3).
// Staged via global_load_lds with inverse-swizzled SOURCE addresses (linear dest).

#define SCL 0.18033688011112042f  /* 0.125 * log2(e) */

DEVI void stage_klds(const u16* __restrict__ Kb, const u16* __restrict__ Vb,
                     u16* sKb, u16* sVb, int kt, int w, int lane) {
  const int kr = lane >> 3;                 // key row 0..7 (+8 for 2nd instr)
  const int kg = (lane & 7) ^ kr;           // source granule (dh/8)
  const u16* gk = Kb + (size_t)(kt + w * 16 + kr) * 64 + kg * 8;
  const int vr = lane >> 2;                 // dh row 0..15 (+16 for 2nd instr)
  const int vg = (lane & 3) ^ (vr & 3);     // source granule (key/8)
  const u16* gv = Vb + (size_t)(w * 32 + vr) * 2048 + kt + vg * 8;
  u16* dk = sKb + w * 1024;
  u16* dv = sVb + w * 1024;
  __builtin_amdgcn_global_load_lds((const __attribute__((address_space(1))) unsigned*)gk,
                                   (__attribute__((address_space(3))) unsigned*)dk, 16, 0, 0);
  __builtin_amdgcn_global_load_lds((const __attribute__((address_space(1))) unsigned*)(gk + 8 * 64),
                                   (__attribute__((address_space(3))) unsigned*)(dk + 512), 16, 0, 0);
  __builtin_amdgcn_global_load_lds((const __attribute__((address_space(1))) unsigned*)gv,
                                   (__attribute__((address_space(3))) unsigned*)dv, 16, 0, 0);
  __builtin_amdgcn_global_load_lds((const __attribute__((address_space(1))) unsigned*)(gv + (size_t)16 * 2048),
                                   (__attribute__((address_space(3))) unsigned*)(dv + 512), 16, 0, 0);
}

__global__ void __launch_bounds__(128, 4)
attn_kernel(const u16* Qp, const u16* __restrict__ Kh,
            const u16* __restrict__ Vt, u16* AO) {
  __shared__ __align__(16) u16 sK[4][2048];
  __shared__ __align__(16) u16 sV[4][2048];
  const int tid = threadIdx.x;
  const int lane = tid & 63;
  const int w = tid >> 6;          // 0..1
  const int lr = lane & 15;
  const int lg = lane >> 4;

  const int id = blockIdx.x;       // 0..1023
  const int xcd = id & 7;
  const int slot = id >> 3;        // 0..127
  const int bh = xcd * 4 + (slot & 3);
  const int x = slot >> 2;         // 0..31
  const int b = bh >> 4;
  const int h = bh & 15;

  const u16* Kb = Kh + (size_t)bh * 2048 * 64;
  const u16* Vb = Vt + (size_t)bh * 64 * 2048;

#pragma unroll 1
  for (int band = 0; band < 2; ++band) {
    const int r0 = 32 * (band ? x : (63 - x));
    const int qrow = r0 + w * 16 + lr;   // this lane's q-row
    const u16* Qw = Qp + ((size_t)(b * 2048 + qrow) << 10) + h * 64;
    const bf16x8 qf0 = *(const bf16x8*)(Qw + lg * 8);
    const bf16x8 qf1 = *(const bf16x8*)(Qw + 32 + lg * 8);

    f32x4 o[4] = {};
    float mr = -INFINITY, ls = 0.f;
    const int nt = (r0 >> 5) + 1;        // tiles; last one masked (for both waves)

    stage_klds(Kb, Vb, sK[0], sV[0], 0, w, lane);
    if (nt > 1) stage_klds(Kb, Vb, sK[1], sV[1], 32, w, lane);

#pragma unroll 1
    for (int t = 0; t < nt; ++t) {
      if (t + 2 < nt) {
        const int bi = (t + 2) & 3;
        stage_klds(Kb, Vb, sK[bi], sV[bi], (t + 2) * 32, w, lane);
        asm volatile("s_waitcnt vmcnt(8)" ::: "memory");
      } else if (t + 1 < nt) {
        asm volatile("s_waitcnt vmcnt(4)" ::: "memory");
      } else {
        asm volatile("s_waitcnt vmcnt(0)" ::: "memory");
      }
      asm volatile("s_barrier" ::: "memory");
      __builtin_amdgcn_s_setprio(1);

      {
        const int bi = t & 3;
        const u16* sKb = sK[bi];
        const u16* sVb = sV[bi];
        const int sw = lr & 7;
        const bf16x8 kf0 = *(const bf16x8*)(sKb + lr * 64 + ((lg ^ sw) * 8));
        const bf16x8 kf1 = *(const bf16x8*)(sKb + lr * 64 + (((4 + lg) ^ sw) * 8));
        const bf16x8 kf2 = *(const bf16x8*)(sKb + (16 + lr) * 64 + ((lg ^ sw) * 8));
        const bf16x8 kf3 = *(const bf16x8*)(sKb + (16 + lr) * 64 + (((4 + lg) ^ sw) * 8));

        const f32x4 z = {};
        f32x4 s0 = __builtin_amdgcn_mfma_f32_16x16x32_bf16(kf0, qf0, z, 0, 0, 0);
        s0 = __builtin_amdgcn_mfma_f32_16x16x32_bf16(kf1, qf1, s0, 0, 0, 0);
        f32x4 s1 = __builtin_amdgcn_mfma_f32_16x16x32_bf16(kf2, qf0, z, 0, 0, 0);
        s1 = __builtin_amdgcn_mfma_f32_16x16x32_bf16(kf3, qf1, s1, 0, 0, 0);

        float p[8];
#pragma unroll
        for (int j = 0; j < 4; ++j) { p[j] = s0[j] * SCL; p[4 + j] = s1[j] * SCL; }
        if (t == nt - 1) {  // wave-uniform: only last tile needs the causal mask
          const int kt0 = t * 32;
#pragma unroll
          for (int j = 0; j < 4; ++j) {
            if (kt0 + lg * 4 + j > qrow)      p[j] = -INFINITY;
            if (kt0 + 16 + lg * 4 + j > qrow) p[4 + j] = -INFINITY;
          }
        }

        const float tm = fmaxf(fmaxf(fmaxf(p[0], p[1]), fmaxf(p[2], p[3])),
                               fmaxf(fmaxf(p[4], p[5]), fmaxf(p[6], p[7])));
        if (!__all(tm <= mr + 11.5f)) {   // rare (and first tile)
          float tr_ = fmaxf(tm, __shfl_xor(tm, 16));
          tr_ = fmaxf(tr_, __shfl_xor(tr_, 32));
          const float mn = fmaxf(mr, tr_);
          const float fac = exp2f(mr - mn);
          mr = mn;
          ls *= fac;
#pragma unroll
          for (int j = 0; j < 4; ++j) {
            const float fj = __shfl(fac, lg * 4 + j);
#pragma unroll
            for (int d = 0; d < 4; ++d) o[d][j] *= fj;
          }
        }

#pragma unroll
        for (int i = 0; i < 8; ++i) p[i] = exp2f(p[i] - mr);
        ls += ((p[0] + p[1]) + (p[2] + p[3])) + ((p[4] + p[5]) + (p[6] + p[7]));

        bf16x8 pa;
#pragma unroll
        for (int i = 0; i < 8; ++i) pa[i] = (short)f2bf(p[i]);

        const int s3 = lr & 3;
#pragma unroll
        for (int d = 0; d < 4; ++d) {
          const u16* vrow = sVb + (16 * d + lr) * 32;
          const s16x4 v0 = *(const s16x4*)(vrow + (((lg >> 1) ^ s3) * 8) + (lg & 1) * 4);
          const s16x4 v1 = *(const s16x4*)(vrow + ((((lg >> 1) + 2) ^ s3) * 8) + (lg & 1) * 4);
          bf16x8 vf;
          vf[0] = v0[0]; vf[1] = v0[1]; vf[2] = v0[2]; vf[3] = v0[3];
          vf[4] = v1[0]; vf[5] = v1[1]; vf[6] = v1[2]; vf[7] = v1[3];
          o[d] = __builtin_amdgcn_mfma_f32_16x16x32_bf16(pa, vf, o[d], 0, 0, 0);
        }
      }
      __builtin_amdgcn_s_setprio(0);
    }

    // finalize: reduce per-lane partial ls across the 4 replicas, then write
    float lt = ls + __shfl_xor(ls, 16);
    lt += __shfl_xor(lt, 32);
    const size_t orow = (size_t)(b * 2048 + r0 + w * 16 + lg * 4);
#pragma unroll
    for (int j = 0; j < 4; ++j) {
      const float inv = 1.0f / __shfl(lt, lg * 4 + j);
#pragma unroll
      for (int d = 0; d < 4; ++d)
        AO[(orow + j) * 1024 + h * 64 + 16 * d + lr] = f2bf(o[d][j] * inv);
    }
    // protect LDS buffers before next band's prologue staging
    asm volatile("s_barrier" ::: "memory");
  }
}

// Host-side bytes/element detection (capture-safe pure host queries).
static int bytes_per_elem(void* p, long long n, void* pnext) {
  if (pnext) {
    ptrdiff_t d = (char*)pnext - (char*)p;
    if (d == n * 2) return 2;
    if (d == n * 4) return 4;
  }
  size_t sz = 0;
  if (hipMemPtrGetInfo(p, &sz) == hipSuccess && sz >= (size_t)(n * 2)) {
    if (sz < (size_t)(n * 4)) return 2;
    if (sz <= (size_t)(n * 8)) return 4;
  }
  return 4;
}

extern "C" void kernel_launch(void* const* d_in, const int* in_sizes, int n_in,
                              void* d_out, int out_size, void* d_ws, size_t ws_size,
                              hipStream_t stream) {
  void* q  = d_in[0];
  void* k  = d_in[1];
  void* v  = d_in[2];
  // d_in[3] = causal tril mask (int32) -- hardcoded in attn_kernel
  void* wq = d_in[4];
  void* wk = d_in[5];
  void* wv = d_in[6];
  void* wo = d_in[7];

  const int in32 = bytes_per_elem(q, in_sizes[0], k) == 4;
  const int w32  = bytes_per_elem(wq, in_sizes[4], wk) == 4;
  const int o32  = bytes_per_elem(d_out, out_size, nullptr) == 4;

  const size_t SZ = (size_t)4096 * 1024;
  u16* Qp = (u16*)d_ws;        // [B,S,D] token-major bf16
  u16* Kh = Qp + SZ;           // [B,H,S,DH] head-major bf16
  u16* Vt = (u16*)d_out;       // [B,H,DH,S] bf16 scratch; overwritten by gemm_out
  u16* AO = Qp;                // attn out aliases Qp (identical element sets per block)

  if (in32)
    gemm_qkv<1><<<dim3(4, 32, 3), 512, 0, stream>>>(q, wq, Qp, k, wk, Kh, v, wv, Vt);
  else
    gemm_qkv<0><<<dim3(4, 32, 3), 512, 0, stream>>>(q, wq, Qp, k, wk, Kh, v, wv, Vt);

  attn_kernel<<<dim3(1024), 128, 0, stream>>>(Qp, Kh, Vt, AO);

  if (w32) {
    if (o32) gemm_out<1, 1><<<dim3(4, 32), 512, 0, stream>>>(AO, wo, d_out);
    else     gemm_out<1, 0><<<dim3(4, 32), 512, 0, stream>>>(AO, wo, d_out);
  } else {
    if (o32) gemm_out<0, 1><<<dim3(4, 32), 512, 0, stream>>>(AO, wo, d_out);
    else     gemm_out<0, 0><<<dim3(4, 32), 512, 0, stream>>>(AO, wo, d_out);
  }
}

// Round 8
// 136.667 us; speedup vs baseline: 2.4810x; 1.0663x over previous
//
#include <hip/hip_runtime.h>
#include <hip/hip_bf16.h>

// B=2, S=2048, D=1024, H=16, DH=64. out = softmax(mask(QK^T/8)) V @ Wo^T, Q=x@Wq^T etc.
// fp32 inputs (detected at launch). Internal: bf16 MFMA, fp32 accum.
// ws (16MB): Qp token-major [B,S,D] (PRE-SCALED by 0.125*log2e) + Kh head-major [B,H,S,DH].
// d_out lower 8MB: Vt transposed [B,H,DH,S] scratch (overwritten by final GEMM).
// AO aliases Qp (per-block element sets identical between read and write).

typedef unsigned short u16;
typedef __attribute__((ext_vector_type(8))) short bf16x8;  // 8 bf16 = 4 VGPR
typedef __attribute__((ext_vector_type(4))) float f32x4;   // MFMA C/D frag
typedef __attribute__((ext_vector_type(4))) short s16x4;

#define DEVI static __device__ __forceinline__
#define SCL 0.18033688011112042f  /* 0.125 * log2(e) */

DEVI u16 f2bf(float f) {
  __hip_bfloat16 h = __float2bfloat16(f);
  union { __hip_bfloat16 h; u16 u; } c; c.h = h;
  return c.u;
}

template <int F32>
DEVI bf16x8 lda8(const void* base, size_t off) {
  if constexpr (!F32) {
    return *(const bf16x8*)((const u16*)base + off);
  } else {
    const float* p = (const float*)base + off;
    f32x4 a = *(const f32x4*)p;
    f32x4 b = *(const f32x4*)(p + 4);
    bf16x8 r;
    r[0] = (short)f2bf(a[0]); r[1] = (short)f2bf(a[1]);
    r[2] = (short)f2bf(a[2]); r[3] = (short)f2bf(a[3]);
    r[4] = (short)f2bf(b[0]); r[5] = (short)f2bf(b[1]);
    r[6] = (short)f2bf(b[2]); r[7] = (short)f2bf(b[3]);
    return r;
  }
}

// C = A[4096,1024] @ W[1024,1024]^T. Tile 128x256, 512 threads (8 waves, 64x64/wave).
// MODE 0: token-major bf16/f32 (scaled by oscale). MODE 1: Vt[((b*16+h)*64+d)*2048+s].
// MODE 2: head-major Kh[((b*16+h)*2048+s)*64+dh].
template <int A32, int W32, int MODE, int O32>
DEVI void gemm_core(u16* sA, u16* sB, const void* A, const void* W, void* C,
                    int tileM, int tileN, float oscale) {
  constexpr int K = 1024, N = 1024;
  const int tid = threadIdx.x;          // 0..511
  const int lane = tid & 63;
  const int wave = tid >> 6;            // 0..7
  const int wr = (wave >> 2) * 64;      // M: {0,64}
  const int wc = (wave & 3) * 64;       // N: {0,64,128,192}
  const int lr = lane & 15;
  const int lg = lane >> 4;

  f32x4 acc[4][4] = {};

  const int ea = tid * 8;               // A: 128x32 = 4096 elems, one round
  const int ra = ea >> 5, ca = ea & 31;
  const int eb1 = 4096 + tid * 8;       // B: 256x32 = 8192 elems, two rounds
  const int rb1 = eb1 >> 5, cb1 = eb1 & 31;

  for (int k0 = 0; k0 < K; k0 += 32) {
    bf16x8 va  = lda8<A32>(A, (size_t)(tileM + ra) * K + ca + k0);
    bf16x8 vb0 = lda8<W32>(W, (size_t)(tileN + ra) * K + ca + k0);
    bf16x8 vb1 = lda8<W32>(W, (size_t)(tileN + rb1) * K + cb1 + k0);
    __syncthreads();
    *(bf16x8*)(sA + ea) = va;
    *(bf16x8*)(sB + ea) = vb0;
    *(bf16x8*)(sB + eb1) = vb1;
    __syncthreads();
    bf16x8 af[4], bfr[4];
#pragma unroll
    for (int m = 0; m < 4; ++m)
      af[m] = *(const bf16x8*)(sA + (wr + m * 16 + lr) * 32 + lg * 8);
#pragma unroll
    for (int n = 0; n < 4; ++n)
      bfr[n] = *(const bf16x8*)(sB + (wc + n * 16 + lr) * 32 + lg * 8);
#pragma unroll
    for (int m = 0; m < 4; ++m)
#pragma unroll
      for (int n = 0; n < 4; ++n)
        acc[m][n] = __builtin_amdgcn_mfma_f32_16x16x32_bf16(af[m], bfr[n], acc[m][n], 0, 0, 0);
  }

  if constexpr (MODE == 0) {
#pragma unroll
    for (int m = 0; m < 4; ++m) {
      const int row0 = tileM + wr + m * 16 + lg * 4;
#pragma unroll
      for (int n = 0; n < 4; ++n) {
        const int col = tileN + wc + n * 16 + lr;
#pragma unroll
        for (int j = 0; j < 4; ++j) {
          if constexpr (O32)
            ((float*)C)[(size_t)(row0 + j) * N + col] = acc[m][n][j] * oscale;
          else
            ((u16*)C)[(size_t)(row0 + j) * N + col] = f2bf(acc[m][n][j] * oscale);
        }
      }
    }
  } else if constexpr (MODE == 1) {
    u16* Cv = (u16*)C;
#pragma unroll
    for (int m = 0; m < 4; ++m) {
      const int row0 = tileM + wr + m * 16 + lg * 4;
      const int bb = row0 >> 11, s0 = row0 & 2047;
#pragma unroll
      for (int n = 0; n < 4; ++n) {
        const int col = tileN + wc + n * 16 + lr;
        s16x4 pk;
#pragma unroll
        for (int j = 0; j < 4; ++j) pk[j] = (short)f2bf(acc[m][n][j]);
        *(s16x4*)(Cv + ((size_t)(col + (bb << 10)) << 11) + s0) = pk;
      }
    }
  } else {  // MODE 2: head-major
    u16* Cv = (u16*)C;
#pragma unroll
    for (int m = 0; m < 4; ++m) {
      const int row0 = tileM + wr + m * 16 + lg * 4;
      const int bb = row0 >> 11, s0 = row0 & 2047;
#pragma unroll
      for (int n = 0; n < 4; ++n) {
        const int col = tileN + wc + n * 16 + lr;
        const size_t base = ((size_t)((bb << 4) + (col >> 6)) * 2048 + s0) * 64 + (col & 63);
#pragma unroll
        for (int j = 0; j < 4; ++j)
          Cv[base + (size_t)j * 64] = f2bf(acc[m][n][j]);
      }
    }
  }
}

// XCD-local tile remap: XCD c owns M-panels [4c,4c+4) x all 4 N-tiles.
DEVI void tile_remap(int& tileM, int& tileN) {
  const int i = blockIdx.x + 4 * blockIdx.y;  // 0..127; XCD = i & 7 (id%8 round-robin)
  const int c = i & 7, s = i >> 3;            // s: 0..15
  tileM = (c * 4 + (s & 3)) * 128;
  tileN = (s >> 2) * 256;
}

template <int IN32>
__global__ void __launch_bounds__(512, 2)
gemm_qkv(const void* __restrict__ q, const void* __restrict__ wq, u16* __restrict__ Qp,
         const void* __restrict__ k, const void* __restrict__ wk, u16* __restrict__ Kh,
         const void* __restrict__ v, const void* __restrict__ wv, u16* __restrict__ Vt) {
  __shared__ u16 sA[128 * 32];
  __shared__ u16 sB[256 * 32];
  int tileM, tileN;
  tile_remap(tileM, tileN);
  if (blockIdx.z == 0)      gemm_core<IN32, IN32, 0, 0>(sA, sB, q, wq, Qp, tileM, tileN, SCL);
  else if (blockIdx.z == 1) gemm_core<IN32, IN32, 2, 0>(sA, sB, k, wk, Kh, tileM, tileN, 1.f);
  else                      gemm_core<IN32, IN32, 1, 0>(sA, sB, v, wv, Vt, tileM, tileN, 1.f);
}

template <int W32, int O32>
__global__ void __launch_bounds__(512, 2)
gemm_out(const u16* __restrict__ A, const void* __restrict__ W, void* __restrict__ C) {
  __shared__ u16 sA[128 * 32];
  __shared__ u16 sB[256 * 32];
  int tileM, tileN;
  tile_remap(tileM, tileN);
  gemm_core<0, W32, 0, O32>(sA, sB, A, W, C, tileM, tileN, 1.f);
}

// ---------------- Flash attention: block-cooperative LDS staging ----------------
// 128-thread blocks (2 waves), ONE 32-row band per block (2048 blocks, heavy-first).
// 32-key tiles TRIPLE-buffered, depth-1 prefetch, ONE barrier per tile.
// Race-freedom: stage(t+1)->(t+1)%3; concurrent computes {t-1,t}: diffs 2,1 mod 3.
// Staleness: per-wave vmcnt(4) drains own stage(t) before the barrier; barrier joins.
// K LDS tile [key 32][dh 64], granule(16B)-swizzle g' = g ^ (key&7)      -> 2-way.
// V LDS tile [dh 64][key 32], granule-swizzle g' = g ^ ((dh>>1)&3)       -> 2-way.
// (V row = 64B: bank = 16*(dh&1) + 4*granule; XOR with (dh>>1)&3 spreads all 8
//  {parity,quad} combos -> 2 lanes/bank-pair = free. Old (dh&3) XOR was 4-way.)
// Staged via global_load_lds with inverse-swizzled SOURCE addresses (linear dest).
// Q is PRE-SCALED by 0.125*log2e in the projection GEMM -> scores land in exp2 domain.

DEVI void stage_klds(const u16* __restrict__ Kb, const u16* __restrict__ Vb,
                     u16* sKb, u16* sVb, int kt, int w, int lane) {
  const int kr = lane >> 3;                 // key row 0..7 (+8 for 2nd instr)
  const int kg = (lane & 7) ^ kr;           // source granule (dh/8)
  const u16* gk = Kb + (size_t)(kt + w * 16 + kr) * 64 + kg * 8;
  const int vr = lane >> 2;                 // dh row 0..15 (+16 for 2nd instr)
  const int vg = (lane & 3) ^ ((lane >> 3) & 3);  // source granule (key/8), sigma=(row>>1)&3
  const u16* gv = Vb + (size_t)(w * 32 + vr) * 2048 + kt + vg * 8;
  u16* dk = sKb + w * 1024;
  u16* dv = sVb + w * 1024;
  __builtin_amdgcn_global_load_lds((const __attribute__((address_space(1))) unsigned*)gk,
                                   (__attribute__((address_space(3))) unsigned*)dk, 16, 0, 0);
  __builtin_amdgcn_global_load_lds((const __attribute__((address_space(1))) unsigned*)(gk + 8 * 64),
                                   (__attribute__((address_space(3))) unsigned*)(dk + 512), 16, 0, 0);
  __builtin_amdgcn_global_load_lds((const __attribute__((address_space(1))) unsigned*)gv,
                                   (__attribute__((address_space(3))) unsigned*)dv, 16, 0, 0);
  __builtin_amdgcn_global_load_lds((const __attribute__((address_space(1))) unsigned*)(gv + (size_t)16 * 2048),
                                   (__attribute__((address_space(3))) unsigned*)(dv + 512), 16, 0, 0);
}

__global__ void __launch_bounds__(128, 3)
attn_kernel(const u16* Qp, const u16* __restrict__ Kh,
            const u16* __restrict__ Vt, u16* AO) {
  __shared__ __align__(16) u16 sK[3][2048];
  __shared__ __align__(16) u16 sV[3][2048];
  const int tid = threadIdx.x;
  const int lane = tid & 63;
  const int w = tid >> 6;          // 0..1
  const int lr = lane & 15;
  const int lg = lane >> 4;

  const int id = blockIdx.x;       // 0..2047
  const int xcd = id & 7;
  const int slot = id >> 3;        // 0..255
  const int bh = xcd * 4 + (slot & 3);
  const int band = 63 - (slot >> 2);  // heavy bands dispatched first
  const int b = bh >> 4;
  const int h = bh & 15;
  const int r0 = band * 32;

  const u16* Kb = Kh + (size_t)bh * 2048 * 64;
  const u16* Vb = Vt + (size_t)bh * 64 * 2048;

  const int qrow = r0 + w * 16 + lr;   // this lane's q-row
  const u16* Qw = Qp + ((size_t)(b * 2048 + qrow) << 10) + h * 64;
  const bf16x8 qf0 = *(const bf16x8*)(Qw + lg * 8);
  const bf16x8 qf1 = *(const bf16x8*)(Qw + 32 + lg * 8);

  f32x4 o[4] = {};
  float mr = -INFINITY, ls = 0.f;
  const int nt = band + 1;             // key tiles; last one masked

  stage_klds(Kb, Vb, sK[0], sV[0], 0, w, lane);

#pragma unroll 1
  for (int t = 0; t < nt; ++t) {
    if (t + 1 < nt) {
      const int bi = (t + 1) % 3;
      stage_klds(Kb, Vb, sK[bi], sV[bi], (t + 1) * 32, w, lane);
      asm volatile("s_waitcnt vmcnt(4)" ::: "memory");
    } else {
      asm volatile("s_waitcnt vmcnt(0)" ::: "memory");
    }
    asm volatile("s_barrier" ::: "memory");
    __builtin_amdgcn_s_setprio(1);

    {
      const int bi = t % 3;
      const u16* sKb = sK[bi];
      const u16* sVb = sV[bi];
      const int sw = lr & 7;
      const bf16x8 kf0 = *(const bf16x8*)(sKb + lr * 64 + ((lg ^ sw) * 8));
      const bf16x8 kf1 = *(const bf16x8*)(sKb + lr * 64 + (((4 + lg) ^ sw) * 8));
      const bf16x8 kf2 = *(const bf16x8*)(sKb + (16 + lr) * 64 + ((lg ^ sw) * 8));
      const bf16x8 kf3 = *(const bf16x8*)(sKb + (16 + lr) * 64 + (((4 + lg) ^ sw) * 8));

      const f32x4 z = {};
      f32x4 s0 = __builtin_amdgcn_mfma_f32_16x16x32_bf16(kf0, qf0, z, 0, 0, 0);
      s0 = __builtin_amdgcn_mfma_f32_16x16x32_bf16(kf1, qf1, s0, 0, 0, 0);
      f32x4 s1 = __builtin_amdgcn_mfma_f32_16x16x32_bf16(kf2, qf0, z, 0, 0, 0);
      s1 = __builtin_amdgcn_mfma_f32_16x16x32_bf16(kf3, qf1, s1, 0, 0, 0);

      float p[8];
#pragma unroll
      for (int j = 0; j < 4; ++j) { p[j] = s0[j]; p[4 + j] = s1[j]; }
      if (t == nt - 1) {  // wave-uniform: only last tile needs the causal mask
        const int kt0 = t * 32;
#pragma unroll
        for (int j = 0; j < 4; ++j) {
          if (kt0 + lg * 4 + j > qrow)      p[j] = -INFINITY;
          if (kt0 + 16 + lg * 4 + j > qrow) p[4 + j] = -INFINITY;
        }
      }

      const float tm = fmaxf(fmaxf(fmaxf(p[0], p[1]), fmaxf(p[2], p[3])),
                             fmaxf(fmaxf(p[4], p[5]), fmaxf(p[6], p[7])));
      if (!__all(tm <= mr + 11.5f)) {   // rare (and first tile)
        float tr_ = fmaxf(tm, __shfl_xor(tm, 16));
        tr_ = fmaxf(tr_, __shfl_xor(tr_, 32));
        const float mn = fmaxf(mr, tr_);
        const float fac = exp2f(mr - mn);
        mr = mn;
        ls *= fac;
#pragma unroll
        for (int j = 0; j < 4; ++j) {
          const float fj = __shfl(fac, lg * 4 + j);
#pragma unroll
          for (int d = 0; d < 4; ++d) o[d][j] *= fj;
        }
      }

#pragma unroll
      for (int i = 0; i < 8; ++i) p[i] = exp2f(p[i] - mr);
      ls += ((p[0] + p[1]) + (p[2] + p[3])) + ((p[4] + p[5]) + (p[6] + p[7]));

      bf16x8 pa;
#pragma unroll
      for (int i = 0; i < 8; ++i) pa[i] = (short)f2bf(p[i]);

      const int s2 = (lr >> 1) & 3;
#pragma unroll
      for (int d = 0; d < 4; ++d) {
        const u16* vrow = sVb + (16 * d + lr) * 32;
        const s16x4 v0 = *(const s16x4*)(vrow + (((lg >> 1) ^ s2) * 8) + (lg & 1) * 4);
        const s16x4 v1 = *(const s16x4*)(vrow + ((((lg >> 1) + 2) ^ s2) * 8) + (lg & 1) * 4);
        bf16x8 vf;
        vf[0] = v0[0]; vf[1] = v0[1]; vf[2] = v0[2]; vf[3] = v0[3];
        vf[4] = v1[0]; vf[5] = v1[1]; vf[6] = v1[2]; vf[7] = v1[3];
        o[d] = __builtin_amdgcn_mfma_f32_16x16x32_bf16(pa, vf, o[d], 0, 0, 0);
      }
    }
    __builtin_amdgcn_s_setprio(0);
  }

  // finalize: reduce per-lane partial ls across the 4 replicas, then write
  float lt = ls + __shfl_xor(ls, 16);
  lt += __shfl_xor(lt, 32);
  const size_t orow = (size_t)(b * 2048 + r0 + w * 16 + lg * 4);
#pragma unroll
  for (int j = 0; j < 4; ++j) {
    const float inv = 1.0f / __shfl(lt, lg * 4 + j);
#pragma unroll
    for (int d = 0; d < 4; ++d)
      AO[(orow + j) * 1024 + h * 64 + 16 * d + lr] = f2bf(o[d][j] * inv);
  }
}

// Host-side bytes/element detection (capture-safe pure host queries).
static int bytes_per_elem(void* p, long long n, void* pnext) {
  if (pnext) {
    ptrdiff_t d = (char*)pnext - (char*)p;
    if (d == n * 2) return 2;
    if (d == n * 4) return 4;
  }
  size_t sz = 0;
  if (hipMemPtrGetInfo(p, &sz) == hipSuccess && sz >= (size_t)(n * 2)) {
    if (sz < (size_t)(n * 4)) return 2;
    if (sz <= (size_t)(n * 8)) return 4;
  }
  return 4;
}

extern "C" void kernel_launch(void* const* d_in, const int* in_sizes, int n_in,
                              void* d_out, int out_size, void* d_ws, size_t ws_size,
                              hipStream_t stream) {
  void* q  = d_in[0];
  void* k  = d_in[1];
  void* v  = d_in[2];
  // d_in[3] = causal tril mask (int32) -- hardcoded in attn_kernel
  void* wq = d_in[4];
  void* wk = d_in[5];
  void* wv = d_in[6];
  void* wo = d_in[7];

  const int in32 = bytes_per_elem(q, in_sizes[0], k) == 4;
  const int w32  = bytes_per_elem(wq, in_sizes[4], wk) == 4;
  const int o32  = bytes_per_elem(d_out, out_size, nullptr) == 4;

  const size_t SZ = (size_t)4096 * 1024;
  u16* Qp = (u16*)d_ws;        // [B,S,D] token-major bf16, pre-scaled by SCL
  u16* Kh = Qp + SZ;           // [B,H,S,DH] head-major bf16
  u16* Vt = (u16*)d_out;       // [B,H,DH,S] bf16 scratch; overwritten by gemm_out
  u16* AO = Qp;                // attn out aliases Qp (identical element sets per block)

  if (in32)
    gemm_qkv<1><<<dim3(4, 32, 3), 512, 0, stream>>>(q, wq, Qp, k, wk, Kh, v, wv, Vt);
  else
    gemm_qkv<0><<<dim3(4, 32, 3), 512, 0, stream>>>(q, wq, Qp, k, wk, Kh, v, wv, Vt);

  attn_kernel<<<dim3(2048), 128, 0, stream>>>(Qp, Kh, Vt, AO);

  if (w32) {
    if (o32) gemm_out<1, 1><<<dim3(4, 32), 512, 0, stream>>>(AO, wo, d_out);
    else     gemm_out<1, 0><<<dim3(4, 32), 512, 0, stream>>>(AO, wo, d_out);
  } else {
    if (o32) gemm_out<0, 1><<<dim3(4, 32), 512, 0, stream>>>(AO, wo, d_out);
    else     gemm_out<0, 0><<<dim3(4, 32), 512, 0, stream>>>(AO, wo, d_out);
  }
}